// Round 7
// baseline (863.379 us; speedup 1.0000x reference)
//
#include <hip/hip_runtime.h>
#include <hip/hip_cooperative_groups.h>
#include <cmath>

namespace cg = cooperative_groups;

#define B 32
#define S 11
#define R 16
#define D 64
#define C 512
#define N 256   // R*R
#define LN_EPS 1e-3f

typedef unsigned short u16;
typedef unsigned int   u32;

using bf16x8 = __attribute__((ext_vector_type(8))) short;
using f32x4  = __attribute__((ext_vector_type(4))) float;

__device__ __forceinline__ float grid_coord(int i) {
    return -1.0f + (2.0f / 15.0f) * (float)i;
}

__device__ __forceinline__ u16 f2bf(float x) {
    union { float f; u32 u; } c; c.f = x;
    u32 r = c.u + 0x7fffu + ((c.u >> 16) & 1u);   // RNE
    return (u16)(r >> 16);
}

// ===================== shared device functions ==============================

// kv-unit: u in [0,704): (bs, half). Phase A: k-logits; Phase B: v-FF.
static __device__ __forceinline__ void kv_unit(
    int u,
    const float* __restrict__ GkT, const float* __restrict__ Gv,
    const float* __restrict__ ewp,
    const float* __restrict__ s_p, const float* __restrict__ s_s,
    const float* __restrict__ w2q, const float* __restrict__ b2q,
    const u16* __restrict__ w2t, const float* __restrict__ mi_b2,
    float* __restrict__ logits, float* __restrict__ v_buf) {
    __shared__ u16 Hs[128 * 128];
    __shared__ float e0s[128], e1s[128], bbk[128], bbv[128];
    __shared__ float wqs[128], lgpart[128], rl0[128], rl1[128];
    int half = u & 1, bs = u >> 1;
    int b = bs / S, s = bs - b * S;
    int t = threadIdx.x;
    __syncthreads();                       // protect shared from previous unit
    if (t < 128) {
        e0s[t] = ewp[t]; e1s[t] = ewp[128 + t];
        bbk[t] = ewp[256 + t]; bbv[t] = ewp[384 + t];
        wqs[t] = w2q[bs * 128 + t];
        float p0 = s_p[bs * 2 + 0], p1 = s_p[bs * 2 + 1];
        float si0 = s_s[bs * 2 + 0], si1 = s_s[bs * 2 + 1];
        int n = half * 128 + t;
        rl0[t] = (grid_coord(n >> 4) - p0) / si0;
        rl1[t] = (grid_coord(n & 15) - p1) / si1;
    }
    __syncthreads();

    // ---- Phase A: k-logits (2 threads per n, j split 64+64), coalesced GkT
    int n_loc = t & 127, jh = t >> 7;
    float accA = 0.f;
    {
        float r0 = rl0[n_loc], r1 = rl1[n_loc];
        const float* Gb = GkT + ((size_t)b * 128 + jh * 64) * 256 + half * 128 + n_loc;
        #pragma unroll 8
        for (int j = 0; j < 64; ++j) {
            int jj = jh * 64 + j;
            float h = Gb[(size_t)j * 256] + r0 * e0s[jj] + r1 * e1s[jj] + bbk[jj];
            accA += fmaxf(h, 0.f) * wqs[jj];
        }
        if (jh) lgpart[n_loc] = accA;
    }
    // ---- Phase B build: flat coalesced Gv read -> rank2 -> relu -> bf16 LDS
    {
        const float4* Gv4 = (const float4*)(Gv + ((size_t)b * 256 + half * 128) * 128);
        #pragma unroll
        for (int it = 0; it < 16; ++it) {
            int f = it * 256 + t;
            int row = f >> 5, j = (f & 31) * 4;
            float4 gv = Gv4[f];
            float r0 = rl0[row], r1 = rl1[row];
            float h0 = fmaxf(gv.x + r0 * e0s[j + 0] + r1 * e1s[j + 0] + bbv[j + 0], 0.f);
            float h1 = fmaxf(gv.y + r0 * e0s[j + 1] + r1 * e1s[j + 1] + bbv[j + 1], 0.f);
            float h2 = fmaxf(gv.z + r0 * e0s[j + 2] + r1 * e1s[j + 2] + bbv[j + 2], 0.f);
            float h3 = fmaxf(gv.w + r0 * e0s[j + 3] + r1 * e1s[j + 3] + bbv[j + 3], 0.f);
            u32 lo = (u32)f2bf(h0) | ((u32)f2bf(h1) << 16);
            u32 hi = (u32)f2bf(h2) | ((u32)f2bf(h3) << 16);
            int js = j ^ ((row & 15) << 3);
            *(uint2*)&Hs[row * 128 + js] = make_uint2(lo, hi);
        }
    }
    __syncthreads();
    if (!jh)
        logits[((size_t)b * S + s) * N + half * 128 + n_loc] = accA + lgpart[n_loc] + b2q[bs];

    // ---- layer2 MFMA: v = H @ W2^T
    int w = t >> 6, l = t & 63;
    int l16 = l & 15, lq = l >> 4;
    f32x4 acc2[2][4];
    #pragma unroll
    for (int mt = 0; mt < 2; ++mt)
        #pragma unroll
        for (int nt = 0; nt < 4; ++nt)
            acc2[mt][nt] = (f32x4){0.f, 0.f, 0.f, 0.f};
    #pragma unroll
    for (int kt = 0; kt < 4; ++kt) {
        bf16x8 af[2], bw[4];
        #pragma unroll
        for (int mt = 0; mt < 2; ++mt) {
            int row = w * 32 + mt * 16 + l16;
            int js = (kt * 32 + lq * 8) ^ ((row & 15) << 3);
            af[mt] = *(const bf16x8*)&Hs[row * 128 + js];
        }
        #pragma unroll
        for (int nt = 0; nt < 4; ++nt) {
            int dd = nt * 16 + l16;
            bw[nt] = *(const bf16x8*)(w2t + dd * 128 + kt * 32 + lq * 8);
        }
        #pragma unroll
        for (int mt = 0; mt < 2; ++mt)
            #pragma unroll
            for (int nt = 0; nt < 4; ++nt)
                acc2[mt][nt] = __builtin_amdgcn_mfma_f32_16x16x32_bf16(af[mt], bw[nt], acc2[mt][nt], 0, 0, 0);
    }
    #pragma unroll
    for (int nt = 0; nt < 4; ++nt) {
        float b2v = mi_b2[nt * 16 + l16];
        #pragma unroll
        for (int mt = 0; mt < 2; ++mt) {
            #pragma unroll
            for (int r = 0; r < 4; ++r) {
                int n = half * 128 + w * 32 + mt * 16 + lq * 4 + r;
                v_buf[((size_t)bs * N + n) * D + nt * 16 + l16] = acc2[mt][nt][r] + b2v;
            }
        }
    }
}

// update-unit: bs in [0,352). ind<3: GRU+MLP+next-q. ind==3: final outputs.
static __device__ __forceinline__ void update_unit(
    int bs, int ind,
    const float* __restrict__ logits, const float* __restrict__ v_buf,
    const float* __restrict__ gru_k, const float* __restrict__ gru_rk,
    const float* __restrict__ gru_b,
    const float* __restrict__ nm_g, const float* __restrict__ nm_b,
    const float* __restrict__ mlp_w1, const float* __restrict__ mlp_b1,
    const float* __restrict__ mlp_w2, const float* __restrict__ mlp_b2,
    const float* __restrict__ ns_g, const float* __restrict__ ns_b,
    const float* __restrict__ pq_w, const float* __restrict__ pq_b,
    const float* __restrict__ mi_w2, const float* __restrict__ mi_b2,
    float* __restrict__ slots, float* __restrict__ out_slots,
    float* __restrict__ s_p, float* __restrict__ s_s,
    float* __restrict__ w2q, float* __restrict__ b2q,
    float* __restrict__ attn_out, float* __restrict__ osp,
    float* __restrict__ oss) {
    __shared__ float a_l[256], part[256], ul[64], hl[64], gx[192], gh[192];
    __shared__ float xl[64], snl[64], hb[128], xq[64], qs[64], red[12];
    int b = bs / S, s = bs - b * S;
    int t = threadIdx.x;
    int wv = t >> 6, l = t & 63, d = l;
    __syncthreads();
    // softmax over slots at n = t  (logits [b][s][n] -> coalesced)
    float m = -1e30f, lg[S];
    #pragma unroll
    for (int ss2 = 0; ss2 < S; ++ss2) {
        lg[ss2] = logits[((size_t)b * S + ss2) * N + t];
        m = fmaxf(m, lg[ss2]);
    }
    float sum = 0.f, e_own = 0.f;
    #pragma unroll
    for (int ss2 = 0; ss2 < S; ++ss2) {
        float e = expf(lg[ss2] - m);
        sum += e;
        if (ss2 == s) e_own = e;
    }
    float a_n = e_own / sum + 1e-8f;
    float g0 = grid_coord(t >> 4), g1 = grid_coord(t & 15);
    float sa = a_n, s0 = a_n * g0, s1 = a_n * g1;
    #pragma unroll
    for (int off = 32; off > 0; off >>= 1) {
        sa += __shfl_xor(sa, off);
        s0 += __shfl_xor(s0, off);
        s1 += __shfl_xor(s1, off);
    }
    if (l == 0) { red[wv] = sa; red[4 + wv] = s0; red[8 + wv] = s1; }
    __syncthreads();
    float SA = red[0] + red[1] + red[2] + red[3];
    float wp0 = (red[4] + red[5] + red[6] + red[7]) / SA;
    float wp1 = (red[8] + red[9] + red[10] + red[11]) / SA;
    float inv_sa = 1.0f / SA;
    float av = a_n * inv_sa + 1e-11f;
    float d0 = g0 - wp0, d1 = g1 - wp1;
    float t0 = d0 * d0 * av, t1 = d1 * d1 * av;
    #pragma unroll
    for (int off = 32; off > 0; off >>= 1) {
        t0 += __shfl_xor(t0, off);
        t1 += __shfl_xor(t1, off);
    }
    __syncthreads();
    if (l == 0) { red[wv] = t0; red[4 + wv] = t1; }
    a_l[t] = a_n * inv_sa;
    __syncthreads();
    float T0c = fminf(fmaxf(sqrtf(red[0] + red[1] + red[2] + red[3]), 0.001f), 5.0f);
    float T1c = fminf(fmaxf(sqrtf(red[4] + red[5] + red[6] + red[7]), 0.001f), 5.0f);

    if (ind == 3) {
        if (t == 0) {
            osp[bs * 2 + 0] = wp0; osp[bs * 2 + 1] = wp1;
            oss[bs * 2 + 0] = T0c; oss[bs * 2 + 1] = T1c;
        }
        attn_out[((size_t)b * N + t) * S + s] = a_n * inv_sa;
        return;
    }
    if (t == 0) {
        s_p[bs * 2 + 0] = wp0; s_p[bs * 2 + 1] = wp1;
        s_s[bs * 2 + 0] = T0c; s_s[bs * 2 + 1] = T1c;
    }
    // updates = sum_n a_l[n] * v[n][d]
    const float* vrow = v_buf + (size_t)bs * N * D;
    float u = 0.f;
    for (int n = wv; n < N; n += 4)
        u += a_l[n] * vrow[n * D + d];
    part[wv * 64 + d] = u;
    __syncthreads();
    if (t < 64) {
        ul[d] = part[d] + part[64 + d] + part[128 + d] + part[192 + d];
        hl[d] = slots[bs * D + d];
    }
    __syncthreads();
    if (t < 192) {
        float ax = gru_b[t], ah = gru_b[192 + t];
        #pragma unroll 8
        for (int i = 0; i < 64; ++i) {
            ax += ul[i] * gru_k[i * 192 + t];
            ah += hl[i] * gru_rk[i * 192 + t];
        }
        gx[t] = ax; gh[t] = ah;
    }
    __syncthreads();
    if (t < 64) {
        float z = 1.f / (1.f + expf(-(gx[d] + gh[d])));
        float r = 1.f / (1.f + expf(-(gx[64 + d] + gh[64 + d])));
        float hc = tanhf(gx[128 + d] + r * gh[128 + d]);
        float sn = z * hl[d] + (1.f - z) * hc;
        snl[d] = sn;
        float sm = sn;
        #pragma unroll
        for (int off = 32; off > 0; off >>= 1) sm += __shfl_xor(sm, off);
        float mm = sm * (1.0f / 64.0f);
        float dx = sn - mm;
        float vs = dx * dx;
        #pragma unroll
        for (int off = 32; off > 0; off >>= 1) vs += __shfl_xor(vs, off);
        float var = vs * (1.0f / 64.0f);
        xl[d] = dx * rsqrtf(var + LN_EPS) * nm_g[d] + nm_b[d];
    }
    __syncthreads();
    if (t < 128) {
        float h1 = mlp_b1[t];
        #pragma unroll 8
        for (int i = 0; i < 64; ++i) h1 += xl[i] * mlp_w1[i * 128 + t];
        hb[t] = fmaxf(h1, 0.f);
    }
    __syncthreads();
    if (t < 64) {
        float o = mlp_b2[d];
        #pragma unroll 8
        for (int j = 0; j < 128; ++j) o += hb[j] * mlp_w2[j * D + d];
        float res = snl[d] + o;
        slots[bs * D + d] = res;
        if (ind == 2) out_slots[bs * D + d] = res;
        float sm = res;
        #pragma unroll
        for (int off = 32; off > 0; off >>= 1) sm += __shfl_xor(sm, off);
        float mm = sm * (1.0f / 64.0f);
        float dx = res - mm;
        float vs = dx * dx;
        #pragma unroll
        for (int off = 32; off > 0; off >>= 1) vs += __shfl_xor(vs, off);
        float var = vs * (1.0f / 64.0f);
        xq[d] = dx * rsqrtf(var + LN_EPS) * ns_g[d] + ns_b[d];
    }
    __syncthreads();
    if (t < 64) {
        float acc = pq_b[d];
        #pragma unroll 8
        for (int i = 0; i < 64; ++i) acc += xq[i] * pq_w[i * D + d];
        qs[d] = acc * 0.125f;
    }
    __syncthreads();
    if (t < 128) {
        float sacc = 0.f;
        #pragma unroll 8
        for (int dd = 0; dd < 64; ++dd) sacc += mi_w2[t * 64 + dd] * qs[dd];
        w2q[bs * 128 + t] = sacc;
    }
    if (t < 64) {
        float v = mi_b2[d] * qs[d];
        #pragma unroll
        for (int off = 32; off > 0; off >>= 1) v += __shfl_xor(v, off);
        if (d == 0) b2q[bs] = v;
    }
}

// ===================== kernels =============================================

__global__ __launch_bounds__(256) void pre1_kernel(
    const float* __restrict__ es_w1, const float* __restrict__ es_b1,
    const float* __restrict__ es_w2, const float* __restrict__ es_b2,
    const float* __restrict__ mi_w1, const float* __restrict__ mi_b1,
    const float* __restrict__ mi_w2,
    const float* __restrict__ pk_w, const float* __restrict__ pk_b,
    const float* __restrict__ pv_w, const float* __restrict__ pv_b,
    const float* __restrict__ er_w, const float* __restrict__ er_b,
    const float* __restrict__ slots_mu, const float* __restrict__ s_p0,
    const float* __restrict__ s_s0,
    float* __restrict__ pos,
    u16* __restrict__ wkT, u16* __restrict__ wvT, u16* __restrict__ w2t,
    float* __restrict__ ewp,
    float* __restrict__ slots, float* __restrict__ s_p, float* __restrict__ s_s) {
    int bid = blockIdx.x;
    int t = threadIdx.x;
    if (bid < 256) {
        int n = bid;
        float g0 = grid_coord(n >> 4), g1 = grid_coord(n & 15);
        __shared__ float h[128];
        if (t < 128) {
            float hj = es_b1[t] + g0 * es_w1[t] + g1 * es_w1[128 + t];
            h[t] = fmaxf(hj, 0.0f);
        }
        __syncthreads();
        #pragma unroll
        for (int c0 = 0; c0 < C; c0 += 256) {
            int c = c0 + t;
            float acc = es_b2[c];
            #pragma unroll 16
            for (int jj = 0; jj < 128; ++jj) acc += h[jj] * es_w2[jj * C + c];
            pos[n * C + c] = acc;
        }
    } else if (bid < 802) {
        int idx = (bid - 256) * 256 + t;
        if (idx < 131072) {
            int mat = idx >> 16;
            int i = idx & 65535;
            int c = i >> 7, j = i & 127;
            const float* pw = mat ? pv_w : pk_w;
            float acc = 0.f;
            #pragma unroll 8
            for (int k = 0; k < 64; ++k) acc += pw[c * 64 + k] * mi_w1[k * 128 + j];
            u16* dst = mat ? wvT : wkT;
            dst[j * 512 + c] = f2bf(acc);
        } else if (idx < 139264) {
            int i = idx - 131072;
            int dd = i >> 7, j = i & 127;
            w2t[i] = f2bf(mi_w2[j * 64 + dd]);
        } else if (idx < 139776) {
            int i = idx - 139264;
            int tt = i >> 7, j = i & 127;
            float acc = 0.f;
            if (tt == 0) {
                for (int k = 0; k < 64; ++k) acc += er_w[k] * mi_w1[k * 128 + j];
            } else if (tt == 1) {
                for (int k = 0; k < 64; ++k) acc += er_w[64 + k] * mi_w1[k * 128 + j];
            } else if (tt == 2) {
                for (int k = 0; k < 64; ++k) acc += (pk_b[k] + er_b[k]) * mi_w1[k * 128 + j];
                acc += mi_b1[j];
            } else {
                for (int k = 0; k < 64; ++k) acc += (pv_b[k] + er_b[k]) * mi_w1[k * 128 + j];
                acc += mi_b1[j];
            }
            ewp[i] = acc;
        }
    } else {
        int idx = (bid - 802) * 256 + t;
        slots[idx] = slots_mu[idx % (S * D)];
        if (idx < B * S * 2) { s_p[idx] = s_p0[idx]; s_s[idx] = s_s0[idx]; }
    }
}

__global__ __launch_bounds__(256) void pre2_kernel(
    const float* __restrict__ inputs, const float* __restrict__ pos,
    const u16* __restrict__ wkT,      // wvT at +65536
    const float* __restrict__ slots,
    const float* __restrict__ ns_g, const float* __restrict__ ns_b,
    const float* __restrict__ pq_w, const float* __restrict__ pq_b,
    const float* __restrict__ mi_w2, const float* __restrict__ mi_b2,
    float* __restrict__ GkT, float* __restrict__ Gv,
    float* __restrict__ w2q, float* __restrict__ b2q) {
    int bid = blockIdx.x;
    int t = threadIdx.x;
    if (bid < 512) {
        int row0 = bid * 16;
        __shared__ u16 Xs[16 * 512];
        const float4* in4 = (const float4*)(inputs + (size_t)row0 * C);
        #pragma unroll
        for (int it = 0; it < 8; ++it) {
            int f = it * 256 + t;
            int lr = f >> 7;
            int c = (f & 127) * 4;
            float4 a = in4[f];
            float4 p = *(const float4*)(pos + (size_t)((row0 + lr) & (N - 1)) * C + c);
            u32 lo = (u32)f2bf(a.x + p.x) | ((u32)f2bf(a.y + p.y) << 16);
            u32 hi = (u32)f2bf(a.z + p.z) | ((u32)f2bf(a.w + p.w) << 16);
            int cs = c ^ ((lr & 7) << 3);
            *(uint2*)&Xs[lr * 512 + cs] = make_uint2(lo, hi);
        }
        __syncthreads();

        int w = t >> 6, l = t & 63;
        int l16 = l & 15, lq = l >> 4;
        int wc = w * 32;
        int b = row0 >> 8, nb = row0 & (N - 1);

        f32x4 acc[2][2];
        #pragma unroll
        for (int m = 0; m < 2; ++m)
            #pragma unroll
            for (int nt = 0; nt < 2; ++nt) acc[m][nt] = (f32x4){0.f, 0.f, 0.f, 0.f};

        for (int kt = 0; kt < 16; ++kt) {
            int k0 = kt * 32 + lq * 8;
            int ks = k0 ^ ((l16 & 7) << 3);
            bf16x8 xf = *(const bf16x8*)&Xs[l16 * 512 + ks];
            #pragma unroll
            for (int m = 0; m < 2; ++m) {
                const u16* Wm = wkT + (size_t)m * 65536;
                #pragma unroll
                for (int nt = 0; nt < 2; ++nt) {
                    bf16x8 wf = *(const bf16x8*)(Wm + (size_t)(wc + nt * 16 + l16) * 512 + k0);
                    acc[m][nt] = __builtin_amdgcn_mfma_f32_16x16x32_bf16(xf, wf, acc[m][nt], 0, 0, 0);
                }
            }
        }
        #pragma unroll
        for (int nt = 0; nt < 2; ++nt) {
            #pragma unroll
            for (int r = 0; r < 4; ++r) {
                int j = wc + nt * 16 + l16;
                int n2 = nb + lq * 4 + r;
                GkT[((size_t)b * 128 + j) * 256 + n2] = acc[0][nt][r];
                Gv[((size_t)b * 256 + n2) * 128 + j] = acc[1][nt][r];
            }
        }
    } else {
        int bs = bid - 512;
        __shared__ float xlds[64], qs[64];
        if (t < 64) {
            float x = slots[bs * D + t];
            float sum = x;
            #pragma unroll
            for (int off = 32; off > 0; off >>= 1) sum += __shfl_xor(sum, off);
            float m = sum * (1.0f / 64.0f);
            float dx = x - m;
            float vs = dx * dx;
            #pragma unroll
            for (int off = 32; off > 0; off >>= 1) vs += __shfl_xor(vs, off);
            float var = vs * (1.0f / 64.0f);
            xlds[t] = dx * rsqrtf(var + LN_EPS) * ns_g[t] + ns_b[t];
        }
        __syncthreads();
        if (t < 64) {
            float acc = pq_b[t];
            #pragma unroll 8
            for (int i = 0; i < 64; ++i) acc += xlds[i] * pq_w[i * D + t];
            qs[t] = acc * 0.125f;
        }
        __syncthreads();
        if (t < 128) {
            float sacc = 0.f;
            #pragma unroll 8
            for (int dd = 0; dd < 64; ++dd) sacc += mi_w2[t * 64 + dd] * qs[dd];
            w2q[bs * 128 + t] = sacc;
        }
        if (t < 64) {
            float v = mi_b2[t] * qs[t];
            #pragma unroll
            for (int off = 32; off > 0; off >>= 1) v += __shfl_xor(v, off);
            if (t == 0) b2q[bs] = v;
        }
    }
}

// Cooperative loop: 256 blocks (guaranteed co-resident), units strided.
__global__ __launch_bounds__(256) void loop_kernel(
    const float* __restrict__ GkT, const float* __restrict__ Gv,
    const float* __restrict__ ewp,
    const u16* __restrict__ w2t, const float* __restrict__ mi_b2,
    const float* __restrict__ gru_k, const float* __restrict__ gru_rk,
    const float* __restrict__ gru_b,
    const float* __restrict__ nm_g, const float* __restrict__ nm_b,
    const float* __restrict__ mlp_w1, const float* __restrict__ mlp_b1,
    const float* __restrict__ mlp_w2, const float* __restrict__ mlp_b2,
    const float* __restrict__ ns_g, const float* __restrict__ ns_b,
    const float* __restrict__ pq_w, const float* __restrict__ pq_b,
    const float* __restrict__ mi_w2,
    float* __restrict__ logits, float* __restrict__ v_buf,
    float* __restrict__ slots, float* __restrict__ s_p, float* __restrict__ s_s,
    float* __restrict__ w2q, float* __restrict__ b2q,
    float* __restrict__ out_slots, float* __restrict__ attn_out,
    float* __restrict__ osp, float* __restrict__ oss) {
    cg::grid_group grid = cg::this_grid();
    for (int ind = 0; ind < 4; ++ind) {
        for (int u = blockIdx.x; u < 704; u += 256)
            kv_unit(u, GkT, Gv, ewp, s_p, s_s, w2q, b2q, w2t, mi_b2, logits, v_buf);
        __threadfence();
        grid.sync();
        for (int u = blockIdx.x; u < 352; u += 256)
            update_unit(u, ind, logits, v_buf, gru_k, gru_rk, gru_b,
                        nm_g, nm_b, mlp_w1, mlp_b1, mlp_w2, mlp_b2,
                        ns_g, ns_b, pq_w, pq_b, mi_w2, mi_b2,
                        slots, out_slots, s_p, s_s, w2q, b2q,
                        attn_out, osp, oss);
        if (ind < 3) {
            __threadfence();
            grid.sync();
        }
    }
}

// Fallback wrappers (plain launches)
__global__ __launch_bounds__(256) void kv_kernel(
    const float* __restrict__ GkT, const float* __restrict__ Gv,
    const float* __restrict__ ewp,
    const float* __restrict__ s_p, const float* __restrict__ s_s,
    const float* __restrict__ w2q, const float* __restrict__ b2q,
    const u16* __restrict__ w2t, const float* __restrict__ mi_b2,
    float* __restrict__ logits, float* __restrict__ v_buf) {
    int orig = blockIdx.x;                       // 704 = 8*88
    int u = (orig & 7) * 88 + (orig >> 3);       // XCD-chunked bijection
    kv_unit(u, GkT, Gv, ewp, s_p, s_s, w2q, b2q, w2t, mi_b2, logits, v_buf);
}

__global__ __launch_bounds__(256) void update_kernel(
    int ind,
    const float* __restrict__ logits, const float* __restrict__ v_buf,
    const float* __restrict__ gru_k, const float* __restrict__ gru_rk,
    const float* __restrict__ gru_b,
    const float* __restrict__ nm_g, const float* __restrict__ nm_b,
    const float* __restrict__ mlp_w1, const float* __restrict__ mlp_b1,
    const float* __restrict__ mlp_w2, const float* __restrict__ mlp_b2,
    const float* __restrict__ ns_g, const float* __restrict__ ns_b,
    const float* __restrict__ pq_w, const float* __restrict__ pq_b,
    const float* __restrict__ mi_w2, const float* __restrict__ mi_b2,
    float* __restrict__ slots, float* __restrict__ out_slots,
    float* __restrict__ s_p, float* __restrict__ s_s,
    float* __restrict__ w2q, float* __restrict__ b2q,
    float* __restrict__ attn_out, float* __restrict__ osp,
    float* __restrict__ oss) {
    int orig = blockIdx.x;                       // 352 = 8*44
    int bs = (orig & 7) * 44 + (orig >> 3);
    update_unit(bs, ind, logits, v_buf, gru_k, gru_rk, gru_b,
                nm_g, nm_b, mlp_w1, mlp_b1, mlp_w2, mlp_b2,
                ns_g, ns_b, pq_w, pq_b, mi_w2, mi_b2,
                slots, out_slots, s_p, s_s, w2q, b2q, attn_out, osp, oss);
}

extern "C" void kernel_launch(void* const* d_in, const int* in_sizes, int n_in,
                              void* d_out, int out_size, void* d_ws, size_t ws_size,
                              hipStream_t stream) {
    const float* inputs  = (const float*)d_in[0];
    const float* s_p0    = (const float*)d_in[1];
    const float* s_s0    = (const float*)d_in[2];
    const float* slots_mu= (const float*)d_in[3];
    const float* es_w1   = (const float*)d_in[4];
    const float* es_b1   = (const float*)d_in[5];
    const float* es_w2   = (const float*)d_in[6];
    const float* es_b2   = (const float*)d_in[7];
    const float* er_w    = (const float*)d_in[8];
    const float* er_b    = (const float*)d_in[9];
    const float* pk_w    = (const float*)d_in[10];
    const float* pk_b    = (const float*)d_in[11];
    const float* pv_w    = (const float*)d_in[12];
    const float* pv_b    = (const float*)d_in[13];
    const float* pq_w    = (const float*)d_in[14];
    const float* pq_b    = (const float*)d_in[15];
    const float* mi_w1   = (const float*)d_in[16];
    const float* mi_b1   = (const float*)d_in[17];
    const float* mi_w2   = (const float*)d_in[18];
    const float* mi_b2   = (const float*)d_in[19];
    const float* ns_g    = (const float*)d_in[20];
    const float* ns_b    = (const float*)d_in[21];
    const float* nm_g    = (const float*)d_in[22];
    const float* nm_b    = (const float*)d_in[23];
    const float* gru_k   = (const float*)d_in[24];
    const float* gru_rk  = (const float*)d_in[25];
    const float* gru_b   = (const float*)d_in[26];
    const float* mlp_w1  = (const float*)d_in[27];
    const float* mlp_b1  = (const float*)d_in[28];
    const float* mlp_w2  = (const float*)d_in[29];
    const float* mlp_b2  = (const float*)d_in[30];

    float* ws    = (float*)d_ws;
    float* pos   = ws;                       // 131072
    float* GkT   = pos   + 131072;           // 1048576
    float* Gv    = GkT   + 1048576;          // 1048576
    float* vb    = Gv    + 1048576;          // 5767168
    float* lgts  = vb    + 5767168;          // 90112
    float* slots = lgts  + 90112;            // 22528
    float* sp    = slots + 22528;            // 704
    float* ssg   = sp    + 704;              // 704
    float* w2qb  = ssg   + 704;              // 45056
    float* b2qb  = w2qb  + 45056;            // 352
    float* ewp   = b2qb  + 352;              // 512
    u16*   wkT   = (u16*)(ewp + 512);        // 65536 u16 (wvT follows)
    u16*   wvT   = wkT + 65536;              // 65536 u16
    u16*   w2t   = wvT + 65536;              // 8192 u16

    float* out      = (float*)d_out;
    float* out_sp   = out + B * S * D;            // 704
    float* out_ss   = out_sp + B * S * 2;         // 704
    float* attn_out = out_ss + B * S * 2;         // 90112

    pre1_kernel<<<890, 256, 0, stream>>>(es_w1, es_b1, es_w2, es_b2,
                                         mi_w1, mi_b1, mi_w2,
                                         pk_w, pk_b, pv_w, pv_b, er_w, er_b,
                                         slots_mu, s_p0, s_s0,
                                         pos, wkT, wvT, w2t, ewp, slots, sp, ssg);
    pre2_kernel<<<864, 256, 0, stream>>>(inputs, pos, wkT, slots,
                                         ns_g, ns_b, pq_w, pq_b, mi_w2, mi_b2,
                                         GkT, Gv, w2qb, b2qb);

    void* args[] = {
        (void*)&GkT, (void*)&Gv, (void*)&ewp, (void*)&w2t, (void*)&mi_b2,
        (void*)&gru_k, (void*)&gru_rk, (void*)&gru_b,
        (void*)&nm_g, (void*)&nm_b,
        (void*)&mlp_w1, (void*)&mlp_b1, (void*)&mlp_w2, (void*)&mlp_b2,
        (void*)&ns_g, (void*)&ns_b, (void*)&pq_w, (void*)&pq_b, (void*)&mi_w2,
        (void*)&lgts, (void*)&vb, (void*)&slots, (void*)&sp, (void*)&ssg,
        (void*)&w2qb, (void*)&b2qb,
        (void*)&out, (void*)&attn_out, (void*)&out_sp, (void*)&out_ss,
    };
    hipError_t cerr = hipLaunchCooperativeKernel((const void*)loop_kernel,
                                                 dim3(256), dim3(256),
                                                 args, 0, stream);
    if (cerr != hipSuccess) {
        (void)hipGetLastError();   // clear sticky error, use fallback path
        for (int ind = 0; ind < 4; ++ind) {
            kv_kernel<<<704, 256, 0, stream>>>(GkT, Gv, ewp, sp, ssg,
                                               w2qb, b2qb, w2t, mi_b2, lgts, vb);
            update_kernel<<<352, 256, 0, stream>>>(ind, lgts, vb,
                                                   gru_k, gru_rk, gru_b,
                                                   nm_g, nm_b, mlp_w1, mlp_b1,
                                                   mlp_w2, mlp_b2, ns_g, ns_b,
                                                   pq_w, pq_b, mi_w2, mi_b2,
                                                   slots, out, sp, ssg,
                                                   w2qb, b2qb,
                                                   attn_out, out_sp, out_ss);
        }
    }
}

// Round 8
// 197.508 us; speedup vs baseline: 4.3714x; 4.3714x over previous
//
#include <hip/hip_runtime.h>
#include <cmath>

#define B 32
#define S 11
#define R 16
#define D 64
#define C 512
#define N 256   // R*R
#define LN_EPS 1e-3f

typedef unsigned short u16;
typedef unsigned int   u32;

using bf16x8 = __attribute__((ext_vector_type(8))) short;
using f32x4  = __attribute__((ext_vector_type(4))) float;

__device__ __forceinline__ float grid_coord(int i) {
    return -1.0f + (2.0f / 15.0f) * (float)i;
}

__device__ __forceinline__ u16 f2bf(float x) {
    union { float f; u32 u; } c; c.f = x;
    u32 r = c.u + 0x7fffu + ((c.u >> 16) & 1u);   // RNE
    return (u16)(r >> 16);
}

// ============ PRE1: pos (blocks 0..255) | wprep (256..801) | init (802..889)
__global__ __launch_bounds__(256) void pre1_kernel(
    const float* __restrict__ es_w1, const float* __restrict__ es_b1,
    const float* __restrict__ es_w2, const float* __restrict__ es_b2,
    const float* __restrict__ mi_w1, const float* __restrict__ mi_b1,
    const float* __restrict__ mi_w2,
    const float* __restrict__ pk_w, const float* __restrict__ pk_b,
    const float* __restrict__ pv_w, const float* __restrict__ pv_b,
    const float* __restrict__ er_w, const float* __restrict__ er_b,
    const float* __restrict__ slots_mu, const float* __restrict__ s_p0,
    const float* __restrict__ s_s0,
    float* __restrict__ pos,
    u16* __restrict__ wkT, u16* __restrict__ wvT, u16* __restrict__ w2t,
    float* __restrict__ ewp,
    float* __restrict__ slots, float* __restrict__ s_p, float* __restrict__ s_s) {
    int bid = blockIdx.x;
    int t = threadIdx.x;
    if (bid < 256) {
        int n = bid;
        float g0 = grid_coord(n >> 4), g1 = grid_coord(n & 15);
        __shared__ float h[128];
        if (t < 128) {
            float hj = es_b1[t] + g0 * es_w1[t] + g1 * es_w1[128 + t];
            h[t] = fmaxf(hj, 0.0f);
        }
        __syncthreads();
        #pragma unroll
        for (int c0 = 0; c0 < C; c0 += 256) {
            int c = c0 + t;
            float acc = es_b2[c];
            #pragma unroll 16
            for (int jj = 0; jj < 128; ++jj) acc += h[jj] * es_w2[jj * C + c];
            pos[n * C + c] = acc;
        }
    } else if (bid < 802) {
        int idx = (bid - 256) * 256 + t;
        if (idx < 131072) {
            int mat = idx >> 16;
            int i = idx & 65535;
            int c = i >> 7, j = i & 127;
            const float* pw = mat ? pv_w : pk_w;
            float acc = 0.f;
            #pragma unroll 8
            for (int k = 0; k < 64; ++k) acc += pw[c * 64 + k] * mi_w1[k * 128 + j];
            u16* dst = mat ? wvT : wkT;
            dst[j * 512 + c] = f2bf(acc);
        } else if (idx < 139264) {
            int i = idx - 131072;
            int dd = i >> 7, j = i & 127;
            w2t[i] = f2bf(mi_w2[j * 64 + dd]);
        } else if (idx < 139776) {
            int i = idx - 139264;
            int tt = i >> 7, j = i & 127;
            float acc = 0.f;
            if (tt == 0) {
                for (int k = 0; k < 64; ++k) acc += er_w[k] * mi_w1[k * 128 + j];
            } else if (tt == 1) {
                for (int k = 0; k < 64; ++k) acc += er_w[64 + k] * mi_w1[k * 128 + j];
            } else if (tt == 2) {
                for (int k = 0; k < 64; ++k) acc += (pk_b[k] + er_b[k]) * mi_w1[k * 128 + j];
                acc += mi_b1[j];
            } else {
                for (int k = 0; k < 64; ++k) acc += (pv_b[k] + er_b[k]) * mi_w1[k * 128 + j];
                acc += mi_b1[j];
            }
            ewp[i] = acc;
        }
    } else {
        int idx = (bid - 802) * 256 + t;
        slots[idx] = slots_mu[idx % (S * D)];
        if (idx < B * S * 2) { s_p[idx] = s_p0[idx]; s_s[idx] = s_s0[idx]; }
    }
}

// ============ PRE2: xw1 (blocks 0..511) | initial qw2q (512..863) ===========
// GkT[b][j][n], Gv[b][n][j]
__global__ __launch_bounds__(256) void pre2_kernel(
    const float* __restrict__ inputs, const float* __restrict__ pos,
    const u16* __restrict__ wkT,      // wvT at +65536
    const float* __restrict__ slots,
    const float* __restrict__ ns_g, const float* __restrict__ ns_b,
    const float* __restrict__ pq_w, const float* __restrict__ pq_b,
    const float* __restrict__ mi_w2, const float* __restrict__ mi_b2,
    float* __restrict__ GkT, float* __restrict__ Gv,
    float* __restrict__ w2q, float* __restrict__ b2q) {
    int bid = blockIdx.x;
    int t = threadIdx.x;
    if (bid < 512) {
        int row0 = bid * 16;
        __shared__ u16 Xs[16 * 512];
        const float4* in4 = (const float4*)(inputs + (size_t)row0 * C);
        #pragma unroll
        for (int it = 0; it < 8; ++it) {
            int f = it * 256 + t;
            int lr = f >> 7;
            int c = (f & 127) * 4;
            float4 a = in4[f];
            float4 p = *(const float4*)(pos + (size_t)((row0 + lr) & (N - 1)) * C + c);
            u32 lo = (u32)f2bf(a.x + p.x) | ((u32)f2bf(a.y + p.y) << 16);
            u32 hi = (u32)f2bf(a.z + p.z) | ((u32)f2bf(a.w + p.w) << 16);
            int cs = c ^ ((lr & 7) << 3);
            *(uint2*)&Xs[lr * 512 + cs] = make_uint2(lo, hi);
        }
        __syncthreads();

        int w = t >> 6, l = t & 63;
        int l16 = l & 15, lq = l >> 4;
        int wc = w * 32;
        int b = row0 >> 8, nb = row0 & (N - 1);

        f32x4 acc[2][2];
        #pragma unroll
        for (int m = 0; m < 2; ++m)
            #pragma unroll
            for (int nt = 0; nt < 2; ++nt) acc[m][nt] = (f32x4){0.f, 0.f, 0.f, 0.f};

        for (int kt = 0; kt < 16; ++kt) {
            int k0 = kt * 32 + lq * 8;
            int ks = k0 ^ ((l16 & 7) << 3);
            bf16x8 xf = *(const bf16x8*)&Xs[l16 * 512 + ks];
            #pragma unroll
            for (int m = 0; m < 2; ++m) {
                const u16* Wm = wkT + (size_t)m * 65536;
                #pragma unroll
                for (int nt = 0; nt < 2; ++nt) {
                    bf16x8 wf = *(const bf16x8*)(Wm + (size_t)(wc + nt * 16 + l16) * 512 + k0);
                    acc[m][nt] = __builtin_amdgcn_mfma_f32_16x16x32_bf16(xf, wf, acc[m][nt], 0, 0, 0);
                }
            }
        }
        #pragma unroll
        for (int nt = 0; nt < 2; ++nt) {
            #pragma unroll
            for (int r = 0; r < 4; ++r) {
                int j = wc + nt * 16 + l16;
                int n2 = nb + lq * 4 + r;
                GkT[((size_t)b * 128 + j) * 256 + n2] = acc[0][nt][r];
                Gv[((size_t)b * 256 + n2) * 128 + j] = acc[1][nt][r];
            }
        }
    } else {
        int bs = bid - 512;
        __shared__ float xlds[64], qs[64];
        if (t < 64) {
            float x = slots[bs * D + t];
            float sum = x;
            #pragma unroll
            for (int off = 32; off > 0; off >>= 1) sum += __shfl_xor(sum, off);
            float m = sum * (1.0f / 64.0f);
            float dx = x - m;
            float vs = dx * dx;
            #pragma unroll
            for (int off = 32; off > 0; off >>= 1) vs += __shfl_xor(vs, off);
            float var = vs * (1.0f / 64.0f);
            xlds[t] = dx * rsqrtf(var + LN_EPS) * ns_g[t] + ns_b[t];
        }
        __syncthreads();
        if (t < 64) {
            float acc = pq_b[t];
            #pragma unroll 8
            for (int i = 0; i < 64; ++i) acc += xlds[i] * pq_w[i * D + t];
            qs[t] = acc * 0.125f;
        }
        __syncthreads();
        if (t < 128) {
            float sacc = 0.f;
            #pragma unroll 8
            for (int dd = 0; dd < 64; ++dd) sacc += mi_w2[t * 64 + dd] * qs[dd];
            w2q[bs * 128 + t] = sacc;
        }
        if (t < 64) {
            float v = mi_b2[t] * qs[t];
            #pragma unroll
            for (int off = 32; off > 0; off >>= 1) v += __shfl_xor(v, off);
            if (t == 0) b2q[bs] = v;
        }
    }
}

// ============ KV0: iteration-0 logits + v (reads global s_p/s_s/w2q) =======
__global__ __launch_bounds__(256) void kv_kernel(
    const float* __restrict__ GkT, const float* __restrict__ Gv,
    const float* __restrict__ ewp,
    const float* __restrict__ s_p, const float* __restrict__ s_s,
    const float* __restrict__ w2q, const float* __restrict__ b2q,
    const u16* __restrict__ w2t, const float* __restrict__ mi_b2,
    float* __restrict__ logits, float* __restrict__ v_buf) {
    int orig = blockIdx.x;                       // 704 = 8*88
    int u = (orig & 7) * 88 + (orig >> 3);       // XCD-chunked bijection
    __shared__ u16 Hs[128 * 128];
    __shared__ float e0s[128], e1s[128], bbk[128], bbv[128];
    __shared__ float wqs[128], lgpart[128], rl0[128], rl1[128];
    int half = u & 1, bs = u >> 1;
    int b = bs / S, s = bs - b * S;
    int t = threadIdx.x;
    if (t < 128) {
        e0s[t] = ewp[t]; e1s[t] = ewp[128 + t];
        bbk[t] = ewp[256 + t]; bbv[t] = ewp[384 + t];
        wqs[t] = w2q[bs * 128 + t];
        float p0 = s_p[bs * 2 + 0], p1 = s_p[bs * 2 + 1];
        float si0 = s_s[bs * 2 + 0], si1 = s_s[bs * 2 + 1];
        int n = half * 128 + t;
        rl0[t] = (grid_coord(n >> 4) - p0) / si0;
        rl1[t] = (grid_coord(n & 15) - p1) / si1;
    }
    __syncthreads();

    int n_loc = t & 127, jh = t >> 7;
    float accA = 0.f;
    {
        float r0 = rl0[n_loc], r1 = rl1[n_loc];
        const float* Gb = GkT + ((size_t)b * 128 + jh * 64) * 256 + half * 128 + n_loc;
        #pragma unroll 8
        for (int j = 0; j < 64; ++j) {
            int jj = jh * 64 + j;
            float h = Gb[(size_t)j * 256] + r0 * e0s[jj] + r1 * e1s[jj] + bbk[jj];
            accA += fmaxf(h, 0.f) * wqs[jj];
        }
        if (jh) lgpart[n_loc] = accA;
    }
    {
        const float4* Gv4 = (const float4*)(Gv + ((size_t)b * 256 + half * 128) * 128);
        #pragma unroll
        for (int it = 0; it < 16; ++it) {
            int f = it * 256 + t;
            int row = f >> 5, j = (f & 31) * 4;
            float4 gv = Gv4[f];
            float r0 = rl0[row], r1 = rl1[row];
            float h0 = fmaxf(gv.x + r0 * e0s[j + 0] + r1 * e1s[j + 0] + bbv[j + 0], 0.f);
            float h1 = fmaxf(gv.y + r0 * e0s[j + 1] + r1 * e1s[j + 1] + bbv[j + 1], 0.f);
            float h2 = fmaxf(gv.z + r0 * e0s[j + 2] + r1 * e1s[j + 2] + bbv[j + 2], 0.f);
            float h3 = fmaxf(gv.w + r0 * e0s[j + 3] + r1 * e1s[j + 3] + bbv[j + 3], 0.f);
            u32 lo = (u32)f2bf(h0) | ((u32)f2bf(h1) << 16);
            u32 hi = (u32)f2bf(h2) | ((u32)f2bf(h3) << 16);
            int js = j ^ ((row & 15) << 3);
            *(uint2*)&Hs[row * 128 + js] = make_uint2(lo, hi);
        }
    }
    __syncthreads();
    if (!jh)
        logits[((size_t)b * S + s) * N + half * 128 + n_loc] = accA + lgpart[n_loc] + b2q[bs];

    int w = t >> 6, l = t & 63;
    int l16 = l & 15, lq = l >> 4;
    f32x4 acc2[2][4];
    #pragma unroll
    for (int mt = 0; mt < 2; ++mt)
        #pragma unroll
        for (int nt = 0; nt < 4; ++nt)
            acc2[mt][nt] = (f32x4){0.f, 0.f, 0.f, 0.f};
    #pragma unroll
    for (int kt = 0; kt < 4; ++kt) {
        bf16x8 af[2], bw[4];
        #pragma unroll
        for (int mt = 0; mt < 2; ++mt) {
            int row = w * 32 + mt * 16 + l16;
            int js = (kt * 32 + lq * 8) ^ ((row & 15) << 3);
            af[mt] = *(const bf16x8*)&Hs[row * 128 + js];
        }
        #pragma unroll
        for (int nt = 0; nt < 4; ++nt) {
            int dd = nt * 16 + l16;
            bw[nt] = *(const bf16x8*)(w2t + dd * 128 + kt * 32 + lq * 8);
        }
        #pragma unroll
        for (int mt = 0; mt < 2; ++mt)
            #pragma unroll
            for (int nt = 0; nt < 4; ++nt)
                acc2[mt][nt] = __builtin_amdgcn_mfma_f32_16x16x32_bf16(af[mt], bw[nt], acc2[mt][nt], 0, 0, 0);
    }
    #pragma unroll
    for (int nt = 0; nt < 4; ++nt) {
        float b2v = mi_b2[nt * 16 + l16];
        #pragma unroll
        for (int mt = 0; mt < 2; ++mt) {
            #pragma unroll
            for (int r = 0; r < 4; ++r) {
                int n = half * 128 + w * 32 + mt * 16 + lq * 4 + r;
                v_buf[((size_t)bs * N + n) * D + nt * 16 + l16] = acc2[mt][nt][r] + b2v;
            }
        }
    }
}

// ============ UPKV: update(ind) + kv(ind+1), fused per bs, 512 threads ======
__global__ __launch_bounds__(512) void upkv_kernel(
    int ind,
    const float* __restrict__ lgts_r, float* __restrict__ lgts_w,
    const float* __restrict__ GkT, const float* __restrict__ Gv,
    const float* __restrict__ ewp,
    const u16* __restrict__ w2t, const float* __restrict__ mi_b2,
    const float* __restrict__ gru_k, const float* __restrict__ gru_rk,
    const float* __restrict__ gru_b,
    const float* __restrict__ nm_g, const float* __restrict__ nm_b,
    const float* __restrict__ mlp_w1, const float* __restrict__ mlp_b1,
    const float* __restrict__ mlp_w2, const float* __restrict__ mlp_b2,
    const float* __restrict__ ns_g, const float* __restrict__ ns_b,
    const float* __restrict__ pq_w, const float* __restrict__ pq_b,
    const float* __restrict__ mi_w2,
    float* __restrict__ v_buf, float* __restrict__ slots,
    float* __restrict__ out_slots) {
    int orig = blockIdx.x;                    // 352 = 8*44
    int bs = (orig & 7) * 44 + (orig >> 3);
    int b = bs / S, s = bs - b * S;
    int t = threadIdx.x;                      // 0..511
    int g = t >> 8, st = t & 255;             // kv subgroup

    __shared__ u16 Hs[2][16384];              // 64 KB (update overlays Hs[0])
    __shared__ float e0s[128], e1s[128], bbk[128], bbv[128], wqs[128];
    __shared__ float rl0[2][128], rl1[2][128], lgp[2][128];
    __shared__ float sc[4];
    float* us  = (float*)&Hs[0][0];
    float* a_l = us;            // 256
    float* part= us + 256;      // 256
    float* ul  = us + 512;      // 64
    float* hl  = us + 576;      // 64
    float* gx  = us + 640;      // 192
    float* gh  = us + 832;      // 192
    float* xl  = us + 1024;     // 64
    float* snl = us + 1088;     // 64
    float* hb  = us + 1152;     // 128
    float* xq  = us + 1280;     // 64
    float* qs  = us + 1344;     // 64
    float* red = us + 1408;     // 12

    if (t < 128) {
        e0s[t] = ewp[t]; e1s[t] = ewp[128 + t];
        bbk[t] = ewp[256 + t]; bbv[t] = ewp[384 + t];
    }

    // ===== Phase U: update(ind) — guarded t<256, block-wide barriers =====
    int wv = t >> 6, l = t & 63, d = l;
    float a_n = 0.f, g0 = 0.f, g1 = 0.f;
    if (t < 256) {
        float m = -1e30f, lg[S];
        #pragma unroll
        for (int ss2 = 0; ss2 < S; ++ss2) {
            lg[ss2] = lgts_r[((size_t)b * S + ss2) * N + t];
            m = fmaxf(m, lg[ss2]);
        }
        float sum = 0.f, e_own = 0.f;
        #pragma unroll
        for (int ss2 = 0; ss2 < S; ++ss2) {
            float e = expf(lg[ss2] - m);
            sum += e;
            if (ss2 == s) e_own = e;
        }
        a_n = e_own / sum + 1e-8f;
        g0 = grid_coord(t >> 4); g1 = grid_coord(t & 15);
        float sa = a_n, s0 = a_n * g0, s1 = a_n * g1;
        #pragma unroll
        for (int off = 32; off > 0; off >>= 1) {
            sa += __shfl_xor(sa, off);
            s0 += __shfl_xor(s0, off);
            s1 += __shfl_xor(s1, off);
        }
        if (l == 0) { red[wv] = sa; red[4 + wv] = s0; red[8 + wv] = s1; }
    }
    __syncthreads();
    float SA = red[0] + red[1] + red[2] + red[3];
    float wp0 = (red[4] + red[5] + red[6] + red[7]) / SA;
    float wp1 = (red[8] + red[9] + red[10] + red[11]) / SA;
    float inv_sa = 1.0f / SA;
    __syncthreads();
    if (t < 256) {
        float av = a_n * inv_sa + 1e-11f;
        float d0 = g0 - wp0, d1 = g1 - wp1;
        float t0 = d0 * d0 * av, t1 = d1 * d1 * av;
        #pragma unroll
        for (int off = 32; off > 0; off >>= 1) {
            t0 += __shfl_xor(t0, off);
            t1 += __shfl_xor(t1, off);
        }
        if (l == 0) { red[wv] = t0; red[4 + wv] = t1; }
        a_l[t] = a_n * inv_sa;
    }
    __syncthreads();
    float T0c = fminf(fmaxf(sqrtf(red[0] + red[1] + red[2] + red[3]), 0.001f), 5.0f);
    float T1c = fminf(fmaxf(sqrtf(red[4] + red[5] + red[6] + red[7]), 0.001f), 5.0f);

    if (t < 256) {
        const float* vrow = v_buf + (size_t)bs * N * D;
        float u = 0.f;
        for (int n = wv; n < N; n += 4)
            u += a_l[n] * vrow[n * D + d];
        part[wv * 64 + d] = u;
    }
    __syncthreads();
    if (t < 64) {
        ul[d] = part[d] + part[64 + d] + part[128 + d] + part[192 + d];
        hl[d] = slots[bs * D + d];
    }
    __syncthreads();
    if (t < 192) {
        float ax = gru_b[t], ah = gru_b[192 + t];
        #pragma unroll 8
        for (int i = 0; i < 64; ++i) {
            ax += ul[i] * gru_k[i * 192 + t];
            ah += hl[i] * gru_rk[i * 192 + t];
        }
        gx[t] = ax; gh[t] = ah;
    }
    __syncthreads();
    if (t < 64) {
        float z = 1.f / (1.f + expf(-(gx[d] + gh[d])));
        float r = 1.f / (1.f + expf(-(gx[64 + d] + gh[64 + d])));
        float hc = tanhf(gx[128 + d] + r * gh[128 + d]);
        float sn = z * hl[d] + (1.f - z) * hc;
        snl[d] = sn;
        float sm = sn;
        #pragma unroll
        for (int off = 32; off > 0; off >>= 1) sm += __shfl_xor(sm, off);
        float mm = sm * (1.0f / 64.0f);
        float dx = sn - mm;
        float vs = dx * dx;
        #pragma unroll
        for (int off = 32; off > 0; off >>= 1) vs += __shfl_xor(vs, off);
        float var = vs * (1.0f / 64.0f);
        xl[d] = dx * rsqrtf(var + LN_EPS) * nm_g[d] + nm_b[d];
    }
    __syncthreads();
    if (t < 128) {
        float h1 = mlp_b1[t];
        #pragma unroll 8
        for (int i = 0; i < 64; ++i) h1 += xl[i] * mlp_w1[i * 128 + t];
        hb[t] = fmaxf(h1, 0.f);
    }
    __syncthreads();
    if (t < 64) {
        float o = mlp_b2[d];
        #pragma unroll 8
        for (int j = 0; j < 128; ++j) o += hb[j] * mlp_w2[j * D + d];
        float res = snl[d] + o;
        slots[bs * D + d] = res;
        if (ind == 2) out_slots[bs * D + d] = res;
        float sm = res;
        #pragma unroll
        for (int off = 32; off > 0; off >>= 1) sm += __shfl_xor(sm, off);
        float mm = sm * (1.0f / 64.0f);
        float dx = res - mm;
        float vs = dx * dx;
        #pragma unroll
        for (int off = 32; off > 0; off >>= 1) vs += __shfl_xor(vs, off);
        float var = vs * (1.0f / 64.0f);
        xq[d] = dx * rsqrtf(var + LN_EPS) * ns_g[d] + ns_b[d];
    }
    __syncthreads();
    if (t < 64) {
        float acc = pq_b[d];
        #pragma unroll 8
        for (int i = 0; i < 64; ++i) acc += xq[i] * pq_w[i * D + d];
        qs[d] = acc * 0.125f;
    }
    __syncthreads();
    float wq_local = 0.f;
    if (t < 128) {
        #pragma unroll 8
        for (int dd = 0; dd < 64; ++dd) wq_local += mi_w2[t * 64 + dd] * qs[dd];
    }
    float b2qv = 0.f;
    if (t < 64) {
        b2qv = mi_b2[d] * qs[d];
        #pragma unroll
        for (int off = 32; off > 0; off >>= 1) b2qv += __shfl_xor(b2qv, off);
    }
    __syncthreads();      // qs reads done; us region (Hs[0]) now dead
    if (t < 128) wqs[t] = wq_local;
    if (t == 0) sc[0] = b2qv;
    if (t < 256) {        // rl for both halves at s_p=wp, s_s=Tc
        int hh = t >> 7, i = t & 127;
        int n = hh * 128 + i;
        rl0[hh][i] = (grid_coord(n >> 4) - wp0) / T0c;
        rl1[hh][i] = (grid_coord(n & 15) - wp1) / T1c;
    }
    __syncthreads();

    // ===== Phase K: kv(ind+1), subgroup g handles half g =====
    int n_loc = st & 127, jh = st >> 7;
    float accA = 0.f;
    {
        float r0 = rl0[g][n_loc], r1 = rl1[g][n_loc];
        const float* Gb = GkT + ((size_t)b * 128 + jh * 64) * 256 + g * 128 + n_loc;
        #pragma unroll 8
        for (int j = 0; j < 64; ++j) {
            int jj = jh * 64 + j;
            float h = Gb[(size_t)j * 256] + r0 * e0s[jj] + r1 * e1s[jj] + bbk[jj];
            accA += fmaxf(h, 0.f) * wqs[jj];
        }
        if (jh) lgp[g][n_loc] = accA;
    }
    {
        const float4* Gv4 = (const float4*)(Gv + ((size_t)b * 256 + g * 128) * 128);
        #pragma unroll
        for (int it = 0; it < 16; ++it) {
            int f = it * 256 + st;
            int row = f >> 5, j = (f & 31) * 4;
            float4 gv = Gv4[f];
            float r0 = rl0[g][row], r1 = rl1[g][row];
            float h0 = fmaxf(gv.x + r0 * e0s[j + 0] + r1 * e1s[j + 0] + bbv[j + 0], 0.f);
            float h1 = fmaxf(gv.y + r0 * e0s[j + 1] + r1 * e1s[j + 1] + bbv[j + 1], 0.f);
            float h2 = fmaxf(gv.z + r0 * e0s[j + 2] + r1 * e1s[j + 2] + bbv[j + 2], 0.f);
            float h3 = fmaxf(gv.w + r0 * e0s[j + 3] + r1 * e1s[j + 3] + bbv[j + 3], 0.f);
            u32 lo = (u32)f2bf(h0) | ((u32)f2bf(h1) << 16);
            u32 hi = (u32)f2bf(h2) | ((u32)f2bf(h3) << 16);
            int js = j ^ ((row & 15) << 3);
            *(uint2*)&Hs[g][row * 128 + js] = make_uint2(lo, hi);
        }
    }
    __syncthreads();
    if (!jh)
        lgts_w[((size_t)b * S + s) * N + g * 128 + n_loc] = accA + lgp[g][n_loc] + sc[0];

    int w = st >> 6, l2 = st & 63;
    int l16 = l2 & 15, lq = l2 >> 4;
    f32x4 acc2[2][4];
    #pragma unroll
    for (int mt = 0; mt < 2; ++mt)
        #pragma unroll
        for (int nt = 0; nt < 4; ++nt)
            acc2[mt][nt] = (f32x4){0.f, 0.f, 0.f, 0.f};
    #pragma unroll
    for (int kt = 0; kt < 4; ++kt) {
        bf16x8 af[2], bw[4];
        #pragma unroll
        for (int mt = 0; mt < 2; ++mt) {
            int row = w * 32 + mt * 16 + l16;
            int js = (kt * 32 + lq * 8) ^ ((row & 15) << 3);
            af[mt] = *(const bf16x8*)&Hs[g][row * 128 + js];
        }
        #pragma unroll
        for (int nt = 0; nt < 4; ++nt) {
            int dd = nt * 16 + l16;
            bw[nt] = *(const bf16x8*)(w2t + dd * 128 + kt * 32 + lq * 8);
        }
        #pragma unroll
        for (int mt = 0; mt < 2; ++mt)
            #pragma unroll
            for (int nt = 0; nt < 4; ++nt)
                acc2[mt][nt] = __builtin_amdgcn_mfma_f32_16x16x32_bf16(af[mt], bw[nt], acc2[mt][nt], 0, 0, 0);
    }
    #pragma unroll
    for (int nt = 0; nt < 4; ++nt) {
        float b2v = mi_b2[nt * 16 + l16];
        #pragma unroll
        for (int mt = 0; mt < 2; ++mt) {
            #pragma unroll
            for (int r = 0; r < 4; ++r) {
                int n = g * 128 + w * 32 + mt * 16 + lq * 4 + r;
                v_buf[((size_t)bs * N + n) * D + nt * 16 + l16] = acc2[mt][nt][r] + b2v;
            }
        }
    }
}

// ============ FIN: final softmax/calcSP -> attn_out, osp, oss ===============
__global__ __launch_bounds__(256) void fin_kernel(
    const float* __restrict__ lgts_r,
    float* __restrict__ attn_out, float* __restrict__ osp, float* __restrict__ oss) {
    int orig = blockIdx.x;
    int bs = (orig & 7) * 44 + (orig >> 3);
    int b = bs / S, s = bs - b * S;
    int t = threadIdx.x;
    int wv = t >> 6, l = t & 63;
    __shared__ float red[12];
    float m = -1e30f, lg[S];
    #pragma unroll
    for (int ss2 = 0; ss2 < S; ++ss2) {
        lg[ss2] = lgts_r[((size_t)b * S + ss2) * N + t];
        m = fmaxf(m, lg[ss2]);
    }
    float sum = 0.f, e_own = 0.f;
    #pragma unroll
    for (int ss2 = 0; ss2 < S; ++ss2) {
        float e = expf(lg[ss2] - m);
        sum += e;
        if (ss2 == s) e_own = e;
    }
    float a_n = e_own / sum + 1e-8f;
    float g0 = grid_coord(t >> 4), g1 = grid_coord(t & 15);
    float sa = a_n, s0 = a_n * g0, s1 = a_n * g1;
    #pragma unroll
    for (int off = 32; off > 0; off >>= 1) {
        sa += __shfl_xor(sa, off);
        s0 += __shfl_xor(s0, off);
        s1 += __shfl_xor(s1, off);
    }
    if (l == 0) { red[wv] = sa; red[4 + wv] = s0; red[8 + wv] = s1; }
    __syncthreads();
    float SA = red[0] + red[1] + red[2] + red[3];
    float wp0 = (red[4] + red[5] + red[6] + red[7]) / SA;
    float wp1 = (red[8] + red[9] + red[10] + red[11]) / SA;
    float inv_sa = 1.0f / SA;
    float av = a_n * inv_sa + 1e-11f;
    float d0 = g0 - wp0, d1 = g1 - wp1;
    float t0 = d0 * d0 * av, t1 = d1 * d1 * av;
    #pragma unroll
    for (int off = 32; off > 0; off >>= 1) {
        t0 += __shfl_xor(t0, off);
        t1 += __shfl_xor(t1, off);
    }
    __syncthreads();
    if (l == 0) { red[wv] = t0; red[4 + wv] = t1; }
    __syncthreads();
    if (t == 0) {
        osp[bs * 2 + 0] = wp0;
        osp[bs * 2 + 1] = wp1;
        oss[bs * 2 + 0] = fminf(fmaxf(sqrtf(red[0] + red[1] + red[2] + red[3]), 0.001f), 5.0f);
        oss[bs * 2 + 1] = fminf(fmaxf(sqrtf(red[4] + red[5] + red[6] + red[7]), 0.001f), 5.0f);
    }
    attn_out[((size_t)b * N + t) * S + s] = a_n * inv_sa;
}

extern "C" void kernel_launch(void* const* d_in, const int* in_sizes, int n_in,
                              void* d_out, int out_size, void* d_ws, size_t ws_size,
                              hipStream_t stream) {
    const float* inputs  = (const float*)d_in[0];
    const float* s_p0    = (const float*)d_in[1];
    const float* s_s0    = (const float*)d_in[2];
    const float* slots_mu= (const float*)d_in[3];
    const float* es_w1   = (const float*)d_in[4];
    const float* es_b1   = (const float*)d_in[5];
    const float* es_w2   = (const float*)d_in[6];
    const float* es_b2   = (const float*)d_in[7];
    const float* er_w    = (const float*)d_in[8];
    const float* er_b    = (const float*)d_in[9];
    const float* pk_w    = (const float*)d_in[10];
    const float* pk_b    = (const float*)d_in[11];
    const float* pv_w    = (const float*)d_in[12];
    const float* pv_b    = (const float*)d_in[13];
    const float* pq_w    = (const float*)d_in[14];
    const float* pq_b    = (const float*)d_in[15];
    const float* mi_w1   = (const float*)d_in[16];
    const float* mi_b1   = (const float*)d_in[17];
    const float* mi_w2   = (const float*)d_in[18];
    const float* mi_b2   = (const float*)d_in[19];
    const float* ns_g    = (const float*)d_in[20];
    const float* ns_b    = (const float*)d_in[21];
    const float* nm_g    = (const float*)d_in[22];
    const float* nm_b    = (const float*)d_in[23];
    const float* gru_k   = (const float*)d_in[24];
    const float* gru_rk  = (const float*)d_in[25];
    const float* gru_b   = (const float*)d_in[26];
    const float* mlp_w1  = (const float*)d_in[27];
    const float* mlp_b1  = (const float*)d_in[28];
    const float* mlp_w2  = (const float*)d_in[29];
    const float* mlp_b2  = (const float*)d_in[30];

    float* ws    = (float*)d_ws;
    float* pos   = ws;                       // 131072
    float* GkT   = pos   + 131072;           // 1048576
    float* Gv    = GkT   + 1048576;          // 1048576
    float* vb    = Gv    + 1048576;          // 5767168
    float* lgts0 = vb    + 5767168;          // 90112
    float* lgts1 = lgts0 + 90112;            // 90112
    float* slots = lgts1 + 90112;            // 22528
    float* sp    = slots + 22528;            // 704
    float* ssg   = sp    + 704;              // 704
    float* w2qb  = ssg   + 704;              // 45056
    float* b2qb  = w2qb  + 45056;            // 352
    float* ewp   = b2qb  + 352;              // 512
    u16*   wkT   = (u16*)(ewp + 512);        // 65536 u16 (wvT follows)
    u16*   wvT   = wkT + 65536;              // 65536 u16
    u16*   w2t   = wvT + 65536;              // 8192 u16

    float* out      = (float*)d_out;
    float* out_sp   = out + B * S * D;            // 704
    float* out_ss   = out_sp + B * S * 2;         // 704
    float* attn_out = out_ss + B * S * 2;         // 90112

    pre1_kernel<<<890, 256, 0, stream>>>(es_w1, es_b1, es_w2, es_b2,
                                         mi_w1, mi_b1, mi_w2,
                                         pk_w, pk_b, pv_w, pv_b, er_w, er_b,
                                         slots_mu, s_p0, s_s0,
                                         pos, wkT, wvT, w2t, ewp, slots, sp, ssg);
    pre2_kernel<<<864, 256, 0, stream>>>(inputs, pos, wkT, slots,
                                         ns_g, ns_b, pq_w, pq_b, mi_w2, mi_b2,
                                         GkT, Gv, w2qb, b2qb);
    kv_kernel<<<704, 256, 0, stream>>>(GkT, Gv, ewp, sp, ssg,
                                       w2qb, b2qb, w2t, mi_b2, lgts0, vb);
    upkv_kernel<<<352, 512, 0, stream>>>(0, lgts0, lgts1, GkT, Gv, ewp, w2t, mi_b2,
                                         gru_k, gru_rk, gru_b, nm_g, nm_b,
                                         mlp_w1, mlp_b1, mlp_w2, mlp_b2,
                                         ns_g, ns_b, pq_w, pq_b, mi_w2,
                                         vb, slots, out);
    upkv_kernel<<<352, 512, 0, stream>>>(1, lgts1, lgts0, GkT, Gv, ewp, w2t, mi_b2,
                                         gru_k, gru_rk, gru_b, nm_g, nm_b,
                                         mlp_w1, mlp_b1, mlp_w2, mlp_b2,
                                         ns_g, ns_b, pq_w, pq_b, mi_w2,
                                         vb, slots, out);
    upkv_kernel<<<352, 512, 0, stream>>>(2, lgts0, lgts1, GkT, Gv, ewp, w2t, mi_b2,
                                         gru_k, gru_rk, gru_b, nm_g, nm_b,
                                         mlp_w1, mlp_b1, mlp_w2, mlp_b2,
                                         ns_g, ns_b, pq_w, pq_b, mi_w2,
                                         vb, slots, out);
    fin_kernel<<<352, 256, 0, stream>>>(lgts1, attn_out, out_sp, out_ss);
}

// Round 9
// 188.015 us; speedup vs baseline: 4.5921x; 1.0505x over previous
//
#include <hip/hip_runtime.h>
#include <cmath>

#define B 32
#define S 11
#define R 16
#define D 64
#define C 512
#define N 256   // R*R
#define LN_EPS 1e-3f

typedef unsigned short u16;
typedef unsigned int   u32;

using bf16x8 = __attribute__((ext_vector_type(8))) short;
using f32x4  = __attribute__((ext_vector_type(4))) float;

__device__ __forceinline__ float grid_coord(int i) {
    return -1.0f + (2.0f / 15.0f) * (float)i;
}

__device__ __forceinline__ u16 f2bf(float x) {
    union { float f; u32 u; } c; c.f = x;
    u32 r = c.u + 0x7fffu + ((c.u >> 16) & 1u);   // RNE
    return (u16)(r >> 16);
}

// ============ PRE1: pos (blocks 0..255) | wprep (256..801) | init (802..889)
__global__ __launch_bounds__(256) void pre1_kernel(
    const float* __restrict__ es_w1, const float* __restrict__ es_b1,
    const float* __restrict__ es_w2, const float* __restrict__ es_b2,
    const float* __restrict__ mi_w1, const float* __restrict__ mi_b1,
    const float* __restrict__ mi_w2,
    const float* __restrict__ pk_w, const float* __restrict__ pk_b,
    const float* __restrict__ pv_w, const float* __restrict__ pv_b,
    const float* __restrict__ er_w, const float* __restrict__ er_b,
    const float* __restrict__ slots_mu, const float* __restrict__ s_p0,
    const float* __restrict__ s_s0,
    float* __restrict__ pos,
    u16* __restrict__ wkT, u16* __restrict__ wvT, u16* __restrict__ w2t,
    float* __restrict__ ewp,
    float* __restrict__ slots, float* __restrict__ s_p, float* __restrict__ s_s) {
    int bid = blockIdx.x;
    int t = threadIdx.x;
    if (bid < 256) {
        int n = bid;
        float g0 = grid_coord(n >> 4), g1 = grid_coord(n & 15);
        __shared__ float h[128];
        if (t < 128) {
            float hj = es_b1[t] + g0 * es_w1[t] + g1 * es_w1[128 + t];
            h[t] = fmaxf(hj, 0.0f);
        }
        __syncthreads();
        #pragma unroll
        for (int c0 = 0; c0 < C; c0 += 256) {
            int c = c0 + t;
            float acc = es_b2[c];
            #pragma unroll 16
            for (int jj = 0; jj < 128; ++jj) acc += h[jj] * es_w2[jj * C + c];
            pos[n * C + c] = acc;
        }
    } else if (bid < 802) {
        int idx = (bid - 256) * 256 + t;
        if (idx < 131072) {
            int mat = idx >> 16;
            int i = idx & 65535;
            int c = i >> 7, j = i & 127;
            const float* pw = mat ? pv_w : pk_w;
            float acc = 0.f;
            #pragma unroll 8
            for (int k = 0; k < 64; ++k) acc += pw[c * 64 + k] * mi_w1[k * 128 + j];
            u16* dst = mat ? wvT : wkT;
            dst[j * 512 + c] = f2bf(acc);
        } else if (idx < 139264) {
            int i = idx - 131072;
            int dd = i >> 7, j = i & 127;
            w2t[i] = f2bf(mi_w2[j * 64 + dd]);
        } else if (idx < 139776) {
            int i = idx - 139264;
            int tt = i >> 7, j = i & 127;
            float acc = 0.f;
            if (tt == 0) {
                for (int k = 0; k < 64; ++k) acc += er_w[k] * mi_w1[k * 128 + j];
            } else if (tt == 1) {
                for (int k = 0; k < 64; ++k) acc += er_w[64 + k] * mi_w1[k * 128 + j];
            } else if (tt == 2) {
                for (int k = 0; k < 64; ++k) acc += (pk_b[k] + er_b[k]) * mi_w1[k * 128 + j];
                acc += mi_b1[j];
            } else {
                for (int k = 0; k < 64; ++k) acc += (pv_b[k] + er_b[k]) * mi_w1[k * 128 + j];
                acc += mi_b1[j];
            }
            ewp[i] = acc;
        }
    } else {
        int idx = (bid - 802) * 256 + t;
        slots[idx] = slots_mu[idx % (S * D)];
        if (idx < B * S * 2) { s_p[idx] = s_p0[idx]; s_s[idx] = s_s0[idx]; }
    }
}

// ============ PRE2: xw1 (blocks 0..511) | initial qw2q (512..863) ===========
// GkT[b][j][n], Gv[b][n][j]
__global__ __launch_bounds__(256) void pre2_kernel(
    const float* __restrict__ inputs, const float* __restrict__ pos,
    const u16* __restrict__ wkT,      // wvT at +65536
    const float* __restrict__ slots,
    const float* __restrict__ ns_g, const float* __restrict__ ns_b,
    const float* __restrict__ pq_w, const float* __restrict__ pq_b,
    const float* __restrict__ mi_w2, const float* __restrict__ mi_b2,
    float* __restrict__ GkT, float* __restrict__ Gv,
    float* __restrict__ w2q, float* __restrict__ b2q) {
    int bid = blockIdx.x;
    int t = threadIdx.x;
    if (bid < 512) {
        int row0 = bid * 16;
        __shared__ u16 Xs[16 * 512];
        const float4* in4 = (const float4*)(inputs + (size_t)row0 * C);
        #pragma unroll
        for (int it = 0; it < 8; ++it) {
            int f = it * 256 + t;
            int lr = f >> 7;
            int c = (f & 127) * 4;
            float4 a = in4[f];
            float4 p = *(const float4*)(pos + (size_t)((row0 + lr) & (N - 1)) * C + c);
            u32 lo = (u32)f2bf(a.x + p.x) | ((u32)f2bf(a.y + p.y) << 16);
            u32 hi = (u32)f2bf(a.z + p.z) | ((u32)f2bf(a.w + p.w) << 16);
            int cs = c ^ ((lr & 7) << 3);
            *(uint2*)&Xs[lr * 512 + cs] = make_uint2(lo, hi);
        }
        __syncthreads();

        int w = t >> 6, l = t & 63;
        int l16 = l & 15, lq = l >> 4;
        int wc = w * 32;
        int b = row0 >> 8, nb = row0 & (N - 1);

        f32x4 acc[2][2];
        #pragma unroll
        for (int m = 0; m < 2; ++m)
            #pragma unroll
            for (int nt = 0; nt < 2; ++nt) acc[m][nt] = (f32x4){0.f, 0.f, 0.f, 0.f};

        for (int kt = 0; kt < 16; ++kt) {
            int k0 = kt * 32 + lq * 8;
            int ks = k0 ^ ((l16 & 7) << 3);
            bf16x8 xf = *(const bf16x8*)&Xs[l16 * 512 + ks];
            #pragma unroll
            for (int m = 0; m < 2; ++m) {
                const u16* Wm = wkT + (size_t)m * 65536;
                #pragma unroll
                for (int nt = 0; nt < 2; ++nt) {
                    bf16x8 wf = *(const bf16x8*)(Wm + (size_t)(wc + nt * 16 + l16) * 512 + k0);
                    acc[m][nt] = __builtin_amdgcn_mfma_f32_16x16x32_bf16(xf, wf, acc[m][nt], 0, 0, 0);
                }
            }
        }
        #pragma unroll
        for (int nt = 0; nt < 2; ++nt) {
            #pragma unroll
            for (int r = 0; r < 4; ++r) {
                int j = wc + nt * 16 + l16;
                int n2 = nb + lq * 4 + r;
                GkT[((size_t)b * 128 + j) * 256 + n2] = acc[0][nt][r];
                Gv[((size_t)b * 256 + n2) * 128 + j] = acc[1][nt][r];
            }
        }
    } else {
        int bs = bid - 512;
        __shared__ float xlds[64], qs[64];
        if (t < 64) {
            float x = slots[bs * D + t];
            float sum = x;
            #pragma unroll
            for (int off = 32; off > 0; off >>= 1) sum += __shfl_xor(sum, off);
            float m = sum * (1.0f / 64.0f);
            float dx = x - m;
            float vs = dx * dx;
            #pragma unroll
            for (int off = 32; off > 0; off >>= 1) vs += __shfl_xor(vs, off);
            float var = vs * (1.0f / 64.0f);
            xlds[t] = dx * rsqrtf(var + LN_EPS) * ns_g[t] + ns_b[t];
        }
        __syncthreads();
        if (t < 64) {
            float acc = pq_b[t];
            #pragma unroll 8
            for (int i = 0; i < 64; ++i) acc += xlds[i] * pq_w[i * D + t];
            qs[t] = acc * 0.125f;
        }
        __syncthreads();
        if (t < 128) {
            float sacc = 0.f;
            #pragma unroll 8
            for (int dd = 0; dd < 64; ++dd) sacc += mi_w2[t * 64 + dd] * qs[dd];
            w2q[bs * 128 + t] = sacc;
        }
        if (t < 64) {
            float v = mi_b2[t] * qs[t];
            #pragma unroll
            for (int off = 32; off > 0; off >>= 1) v += __shfl_xor(v, off);
            if (t == 0) b2q[bs] = v;
        }
    }
}

// ============ KV0: iteration-0 logits + v, reg-H layer2 (no Hs LDS) ========
__global__ __launch_bounds__(256) void kv_kernel(
    const float* __restrict__ GkT, const float* __restrict__ Gv,
    const float* __restrict__ ewp,
    const float* __restrict__ s_p, const float* __restrict__ s_s,
    const float* __restrict__ w2q, const float* __restrict__ b2q,
    const u16* __restrict__ w2t, const float* __restrict__ mi_b2,
    float* __restrict__ logits, float* __restrict__ v_buf) {
    int orig = blockIdx.x;                       // 704 = 8*88
    int u = (orig & 7) * 88 + (orig >> 3);       // XCD-chunked bijection
    __shared__ float e0s[128], e1s[128], bbk[128], bbv[128];
    __shared__ float wqs[128], lgpart[128], rl0[128], rl1[128];
    int half = u & 1, bs = u >> 1;
    int b = bs / S, s = bs - b * S;
    int t = threadIdx.x;
    if (t < 128) {
        e0s[t] = ewp[t]; e1s[t] = ewp[128 + t];
        bbk[t] = ewp[256 + t]; bbv[t] = ewp[384 + t];
        wqs[t] = w2q[bs * 128 + t];
        float p0 = s_p[bs * 2 + 0], p1 = s_p[bs * 2 + 1];
        float si0 = s_s[bs * 2 + 0], si1 = s_s[bs * 2 + 1];
        int n = half * 128 + t;
        rl0[t] = (grid_coord(n >> 4) - p0) / si0;
        rl1[t] = (grid_coord(n & 15) - p1) / si1;
    }
    __syncthreads();

    // ---- Phase A: k-logits ----
    int n_loc = t & 127, jh = t >> 7;
    float accA = 0.f;
    {
        float r0 = rl0[n_loc], r1 = rl1[n_loc];
        const float* Gb = GkT + ((size_t)b * 128 + jh * 64) * 256 + half * 128 + n_loc;
        #pragma unroll 8
        for (int j = 0; j < 64; ++j) {
            int jj = jh * 64 + j;
            float h = Gb[(size_t)j * 256] + r0 * e0s[jj] + r1 * e1s[jj] + bbk[jj];
            accA += fmaxf(h, 0.f) * wqs[jj];
        }
        if (jh) lgpart[n_loc] = accA;
    }
    __syncthreads();
    if (!jh)
        logits[((size_t)b * S + s) * N + half * 128 + n_loc] = accA + lgpart[n_loc] + b2q[bs];

    // ---- Phase B: reg-H layer2 MFMA (H computed per-lane from Gv) ----
    int w = t >> 6, l = t & 63;
    int l16 = l & 15, lq = l >> 4;
    f32x4 acc2[2][4];
    #pragma unroll
    for (int mt = 0; mt < 2; ++mt)
        #pragma unroll
        for (int nt = 0; nt < 4; ++nt)
            acc2[mt][nt] = (f32x4){0.f, 0.f, 0.f, 0.f};
    #pragma unroll
    for (int kt = 0; kt < 4; ++kt) {
        int j0 = kt * 32 + lq * 8;
        float4 e0a = *(const float4*)&e0s[j0], e0b = *(const float4*)&e0s[j0 + 4];
        float4 e1a = *(const float4*)&e1s[j0], e1b = *(const float4*)&e1s[j0 + 4];
        float4 bba = *(const float4*)&bbv[j0], bbb = *(const float4*)&bbv[j0 + 4];
        bf16x8 af[2], bw[4];
        #pragma unroll
        for (int mt = 0; mt < 2; ++mt) {
            int row = w * 32 + mt * 16 + l16;
            float r0 = rl0[row], r1 = rl1[row];
            const float* Gr = Gv + ((size_t)b * 256 + half * 128 + row) * 128 + j0;
            float4 ga = *(const float4*)Gr;
            float4 gb = *(const float4*)(Gr + 4);
            float h0 = fmaxf(ga.x + r0 * e0a.x + r1 * e1a.x + bba.x, 0.f);
            float h1 = fmaxf(ga.y + r0 * e0a.y + r1 * e1a.y + bba.y, 0.f);
            float h2 = fmaxf(ga.z + r0 * e0a.z + r1 * e1a.z + bba.z, 0.f);
            float h3 = fmaxf(ga.w + r0 * e0a.w + r1 * e1a.w + bba.w, 0.f);
            float h4 = fmaxf(gb.x + r0 * e0b.x + r1 * e1b.x + bbb.x, 0.f);
            float h5 = fmaxf(gb.y + r0 * e0b.y + r1 * e1b.y + bbb.y, 0.f);
            float h6 = fmaxf(gb.z + r0 * e0b.z + r1 * e1b.z + bbb.z, 0.f);
            float h7 = fmaxf(gb.w + r0 * e0b.w + r1 * e1b.w + bbb.w, 0.f);
            union { bf16x8 v; u32 q[4]; } pk;
            pk.q[0] = (u32)f2bf(h0) | ((u32)f2bf(h1) << 16);
            pk.q[1] = (u32)f2bf(h2) | ((u32)f2bf(h3) << 16);
            pk.q[2] = (u32)f2bf(h4) | ((u32)f2bf(h5) << 16);
            pk.q[3] = (u32)f2bf(h6) | ((u32)f2bf(h7) << 16);
            af[mt] = pk.v;
        }
        #pragma unroll
        for (int nt = 0; nt < 4; ++nt) {
            int dd = nt * 16 + l16;
            bw[nt] = *(const bf16x8*)(w2t + dd * 128 + j0);
        }
        #pragma unroll
        for (int mt = 0; mt < 2; ++mt)
            #pragma unroll
            for (int nt = 0; nt < 4; ++nt)
                acc2[mt][nt] = __builtin_amdgcn_mfma_f32_16x16x32_bf16(af[mt], bw[nt], acc2[mt][nt], 0, 0, 0);
    }
    #pragma unroll
    for (int nt = 0; nt < 4; ++nt) {
        float b2v = mi_b2[nt * 16 + l16];
        #pragma unroll
        for (int mt = 0; mt < 2; ++mt) {
            #pragma unroll
            for (int r = 0; r < 4; ++r) {
                int n = half * 128 + w * 32 + mt * 16 + lq * 4 + r;
                v_buf[((size_t)bs * N + n) * D + nt * 16 + l16] = acc2[mt][nt][r] + b2v;
            }
        }
    }
}

// ============ UPKV: update(ind) + kv(ind+1), fused per bs, 512 threads ======
__global__ __launch_bounds__(512) void upkv_kernel(
    int ind,
    const float* __restrict__ lgts_r, float* __restrict__ lgts_w,
    const float* __restrict__ GkT, const float* __restrict__ Gv,
    const float* __restrict__ ewp,
    const u16* __restrict__ w2t, const float* __restrict__ mi_b2,
    const float* __restrict__ gru_k, const float* __restrict__ gru_rk,
    const float* __restrict__ gru_b,
    const float* __restrict__ nm_g, const float* __restrict__ nm_b,
    const float* __restrict__ mlp_w1, const float* __restrict__ mlp_b1,
    const float* __restrict__ mlp_w2, const float* __restrict__ mlp_b2,
    const float* __restrict__ ns_g, const float* __restrict__ ns_b,
    const float* __restrict__ pq_w, const float* __restrict__ pq_b,
    const float* __restrict__ mi_w2,
    float* __restrict__ v_buf, float* __restrict__ slots,
    float* __restrict__ out_slots) {
    int orig = blockIdx.x;                    // 352 = 8*44
    int bs = (orig & 7) * 44 + (orig >> 3);
    int b = bs / S, s = bs - b * S;
    int t = threadIdx.x;                      // 0..511
    int g = t >> 8, st = t & 255;             // kv subgroup

    __shared__ float e0s[128], e1s[128], bbk[128], bbv[128], wqs[128];
    __shared__ float rl0[2][128], rl1[2][128], lgp[2][128];
    __shared__ float a_l[256], part[512], ul[64], hl[64], gx[192], gh[192];
    __shared__ float xl[64], snl[64], hb[128], xq[64], qs[64], red[12], sc[4];

    if (t < 128) {
        e0s[t] = ewp[t]; e1s[t] = ewp[128 + t];
        bbk[t] = ewp[256 + t]; bbv[t] = ewp[384 + t];
    }

    // ===== Phase U: update(ind) =====
    int wv = t >> 6, l = t & 63, d = l;
    float a_n = 0.f, g0 = 0.f, g1 = 0.f;
    if (t < 256) {
        float m = -1e30f, lg[S];
        #pragma unroll
        for (int ss2 = 0; ss2 < S; ++ss2) {
            lg[ss2] = lgts_r[((size_t)b * S + ss2) * N + t];
            m = fmaxf(m, lg[ss2]);
        }
        float sum = 0.f, e_own = 0.f;
        #pragma unroll
        for (int ss2 = 0; ss2 < S; ++ss2) {
            float e = expf(lg[ss2] - m);
            sum += e;
            if (ss2 == s) e_own = e;
        }
        a_n = e_own / sum + 1e-8f;
        g0 = grid_coord(t >> 4); g1 = grid_coord(t & 15);
        float sa = a_n, s0 = a_n * g0, s1 = a_n * g1;
        #pragma unroll
        for (int off = 32; off > 0; off >>= 1) {
            sa += __shfl_xor(sa, off);
            s0 += __shfl_xor(s0, off);
            s1 += __shfl_xor(s1, off);
        }
        if (l == 0) { red[wv] = sa; red[4 + wv] = s0; red[8 + wv] = s1; }
    }
    __syncthreads();
    float SA = red[0] + red[1] + red[2] + red[3];
    float wp0 = (red[4] + red[5] + red[6] + red[7]) / SA;
    float wp1 = (red[8] + red[9] + red[10] + red[11]) / SA;
    float inv_sa = 1.0f / SA;
    __syncthreads();
    if (t < 256) {
        float av = a_n * inv_sa + 1e-11f;
        float d0 = g0 - wp0, d1 = g1 - wp1;
        float t0 = d0 * d0 * av, t1 = d1 * d1 * av;
        #pragma unroll
        for (int off = 32; off > 0; off >>= 1) {
            t0 += __shfl_xor(t0, off);
            t1 += __shfl_xor(t1, off);
        }
        if (l == 0) { red[wv] = t0; red[4 + wv] = t1; }
        a_l[t] = a_n * inv_sa;
    }
    __syncthreads();
    float T0c = fminf(fmaxf(sqrtf(red[0] + red[1] + red[2] + red[3]), 0.001f), 5.0f);
    float T1c = fminf(fmaxf(sqrtf(red[4] + red[5] + red[6] + red[7]), 0.001f), 5.0f);

    {   // updates split 8 ways over n
        const float* vrow = v_buf + (size_t)bs * N * D;
        float u = 0.f;
        for (int n = wv; n < N; n += 8)
            u += a_l[n] * vrow[n * D + d];
        part[wv * 64 + d] = u;
    }
    __syncthreads();
    if (t < 64) {
        float uu = 0.f;
        #pragma unroll
        for (int p = 0; p < 8; ++p) uu += part[p * 64 + d];
        ul[d] = uu;
        hl[d] = slots[bs * D + d];
    }
    __syncthreads();
    if (t < 192) {
        float ax = gru_b[t], ah = gru_b[192 + t];
        #pragma unroll 8
        for (int i = 0; i < 64; ++i) {
            ax += ul[i] * gru_k[i * 192 + t];
            ah += hl[i] * gru_rk[i * 192 + t];
        }
        gx[t] = ax; gh[t] = ah;
    }
    __syncthreads();
    if (t < 64) {
        float z = 1.f / (1.f + expf(-(gx[d] + gh[d])));
        float r = 1.f / (1.f + expf(-(gx[64 + d] + gh[64 + d])));
        float hc = tanhf(gx[128 + d] + r * gh[128 + d]);
        float sn = z * hl[d] + (1.f - z) * hc;
        snl[d] = sn;
        float sm = sn;
        #pragma unroll
        for (int off = 32; off > 0; off >>= 1) sm += __shfl_xor(sm, off);
        float mm = sm * (1.0f / 64.0f);
        float dx = sn - mm;
        float vs = dx * dx;
        #pragma unroll
        for (int off = 32; off > 0; off >>= 1) vs += __shfl_xor(vs, off);
        float var = vs * (1.0f / 64.0f);
        xl[d] = dx * rsqrtf(var + LN_EPS) * nm_g[d] + nm_b[d];
    }
    __syncthreads();
    if (t < 128) {
        float h1 = mlp_b1[t];
        #pragma unroll 8
        for (int i = 0; i < 64; ++i) h1 += xl[i] * mlp_w1[i * 128 + t];
        hb[t] = fmaxf(h1, 0.f);
    }
    __syncthreads();
    if (t < 64) {
        float o = mlp_b2[d];
        #pragma unroll 8
        for (int j = 0; j < 128; ++j) o += hb[j] * mlp_w2[j * D + d];
        float res = snl[d] + o;
        slots[bs * D + d] = res;
        if (ind == 2) out_slots[bs * D + d] = res;
        float sm = res;
        #pragma unroll
        for (int off = 32; off > 0; off >>= 1) sm += __shfl_xor(sm, off);
        float mm = sm * (1.0f / 64.0f);
        float dx = res - mm;
        float vs = dx * dx;
        #pragma unroll
        for (int off = 32; off > 0; off >>= 1) vs += __shfl_xor(vs, off);
        float var = vs * (1.0f / 64.0f);
        xq[d] = dx * rsqrtf(var + LN_EPS) * ns_g[d] + ns_b[d];
    }
    __syncthreads();
    if (t < 64) {
        float acc = pq_b[d];
        #pragma unroll 8
        for (int i = 0; i < 64; ++i) acc += xq[i] * pq_w[i * D + d];
        qs[d] = acc * 0.125f;
    }
    __syncthreads();
    float wq_local = 0.f;
    if (t < 128) {
        #pragma unroll 8
        for (int dd = 0; dd < 64; ++dd) wq_local += mi_w2[t * 64 + dd] * qs[dd];
    }
    float b2qv = 0.f;
    if (t < 64) {
        b2qv = mi_b2[d] * qs[d];
        #pragma unroll
        for (int off = 32; off > 0; off >>= 1) b2qv += __shfl_xor(b2qv, off);
    }
    if (t < 128) wqs[t] = wq_local;
    if (t == 0) sc[0] = b2qv;
    if (t < 256) {
        int hh = t >> 7, i = t & 127;
        int n = hh * 128 + i;
        rl0[hh][i] = (grid_coord(n >> 4) - wp0) / T0c;
        rl1[hh][i] = (grid_coord(n & 15) - wp1) / T1c;
    }
    __syncthreads();

    // ===== Phase K: kv(ind+1), subgroup g handles half g =====
    int n_loc = st & 127, jh = st >> 7;
    float accA = 0.f;
    {
        float r0 = rl0[g][n_loc], r1 = rl1[g][n_loc];
        const float* Gb = GkT + ((size_t)b * 128 + jh * 64) * 256 + g * 128 + n_loc;
        #pragma unroll 8
        for (int j = 0; j < 64; ++j) {
            int jj = jh * 64 + j;
            float h = Gb[(size_t)j * 256] + r0 * e0s[jj] + r1 * e1s[jj] + bbk[jj];
            accA += fmaxf(h, 0.f) * wqs[jj];
        }
        if (jh) lgp[g][n_loc] = accA;
    }
    __syncthreads();
    if (!jh)
        lgts_w[((size_t)b * S + s) * N + g * 128 + n_loc] = accA + lgp[g][n_loc] + sc[0];

    // reg-H layer2
    int w = st >> 6, l2 = st & 63;
    int l16 = l2 & 15, lq = l2 >> 4;
    f32x4 acc2[2][4];
    #pragma unroll
    for (int mt = 0; mt < 2; ++mt)
        #pragma unroll
        for (int nt = 0; nt < 4; ++nt)
            acc2[mt][nt] = (f32x4){0.f, 0.f, 0.f, 0.f};
    #pragma unroll
    for (int kt = 0; kt < 4; ++kt) {
        int j0 = kt * 32 + lq * 8;
        float4 e0a = *(const float4*)&e0s[j0], e0b = *(const float4*)&e0s[j0 + 4];
        float4 e1a = *(const float4*)&e1s[j0], e1b = *(const float4*)&e1s[j0 + 4];
        float4 bba = *(const float4*)&bbv[j0], bbb = *(const float4*)&bbv[j0 + 4];
        bf16x8 af[2], bw[4];
        #pragma unroll
        for (int mt = 0; mt < 2; ++mt) {
            int row = w * 32 + mt * 16 + l16;
            float r0 = rl0[g][row], r1 = rl1[g][row];
            const float* Gr = Gv + ((size_t)b * 256 + g * 128 + row) * 128 + j0;
            float4 ga = *(const float4*)Gr;
            float4 gb = *(const float4*)(Gr + 4);
            float h0 = fmaxf(ga.x + r0 * e0a.x + r1 * e1a.x + bba.x, 0.f);
            float h1 = fmaxf(ga.y + r0 * e0a.y + r1 * e1a.y + bba.y, 0.f);
            float h2 = fmaxf(ga.z + r0 * e0a.z + r1 * e1a.z + bba.z, 0.f);
            float h3 = fmaxf(ga.w + r0 * e0a.w + r1 * e1a.w + bba.w, 0.f);
            float h4 = fmaxf(gb.x + r0 * e0b.x + r1 * e1b.x + bbb.x, 0.f);
            float h5 = fmaxf(gb.y + r0 * e0b.y + r1 * e1b.y + bbb.y, 0.f);
            float h6 = fmaxf(gb.z + r0 * e0b.z + r1 * e1b.z + bbb.z, 0.f);
            float h7 = fmaxf(gb.w + r0 * e0b.w + r1 * e1b.w + bbb.w, 0.f);
            union { bf16x8 v; u32 q[4]; } pk;
            pk.q[0] = (u32)f2bf(h0) | ((u32)f2bf(h1) << 16);
            pk.q[1] = (u32)f2bf(h2) | ((u32)f2bf(h3) << 16);
            pk.q[2] = (u32)f2bf(h4) | ((u32)f2bf(h5) << 16);
            pk.q[3] = (u32)f2bf(h6) | ((u32)f2bf(h7) << 16);
            af[mt] = pk.v;
        }
        #pragma unroll
        for (int nt = 0; nt < 4; ++nt) {
            int dd = nt * 16 + l16;
            bw[nt] = *(const bf16x8*)(w2t + dd * 128 + j0);
        }
        #pragma unroll
        for (int mt = 0; mt < 2; ++mt)
            #pragma unroll
            for (int nt = 0; nt < 4; ++nt)
                acc2[mt][nt] = __builtin_amdgcn_mfma_f32_16x16x32_bf16(af[mt], bw[nt], acc2[mt][nt], 0, 0, 0);
    }
    #pragma unroll
    for (int nt = 0; nt < 4; ++nt) {
        float b2v = mi_b2[nt * 16 + l16];
        #pragma unroll
        for (int mt = 0; mt < 2; ++mt) {
            #pragma unroll
            for (int r = 0; r < 4; ++r) {
                int n = g * 128 + w * 32 + mt * 16 + lq * 4 + r;
                v_buf[((size_t)bs * N + n) * D + nt * 16 + l16] = acc2[mt][nt][r] + b2v;
            }
        }
    }
}

// ============ FIN: final softmax/calcSP -> attn_out, osp, oss ===============
__global__ __launch_bounds__(256) void fin_kernel(
    const float* __restrict__ lgts_r,
    float* __restrict__ attn_out, float* __restrict__ osp, float* __restrict__ oss) {
    int orig = blockIdx.x;
    int bs = (orig & 7) * 44 + (orig >> 3);
    int b = bs / S, s = bs - b * S;
    int t = threadIdx.x;
    int wv = t >> 6, l = t & 63;
    __shared__ float red[12];
    float m = -1e30f, lg[S];
    #pragma unroll
    for (int ss2 = 0; ss2 < S; ++ss2) {
        lg[ss2] = lgts_r[((size_t)b * S + ss2) * N + t];
        m = fmaxf(m, lg[ss2]);
    }
    float sum = 0.f, e_own = 0.f;
    #pragma unroll
    for (int ss2 = 0; ss2 < S; ++ss2) {
        float e = expf(lg[ss2] - m);
        sum += e;
        if (ss2 == s) e_own = e;
    }
    float a_n = e_own / sum + 1e-8f;
    float g0 = grid_coord(t >> 4), g1 = grid_coord(t & 15);
    float sa = a_n, s0 = a_n * g0, s1 = a_n * g1;
    #pragma unroll
    for (int off = 32; off > 0; off >>= 1) {
        sa += __shfl_xor(sa, off);
        s0 += __shfl_xor(s0, off);
        s1 += __shfl_xor(s1, off);
    }
    if (l == 0) { red[wv] = sa; red[4 + wv] = s0; red[8 + wv] = s1; }
    __syncthreads();
    float SA = red[0] + red[1] + red[2] + red[3];
    float wp0 = (red[4] + red[5] + red[6] + red[7]) / SA;
    float wp1 = (red[8] + red[9] + red[10] + red[11]) / SA;
    float inv_sa = 1.0f / SA;
    float av = a_n * inv_sa + 1e-11f;
    float d0 = g0 - wp0, d1 = g1 - wp1;
    float t0 = d0 * d0 * av, t1 = d1 * d1 * av;
    #pragma unroll
    for (int off = 32; off > 0; off >>= 1) {
        t0 += __shfl_xor(t0, off);
        t1 += __shfl_xor(t1, off);
    }
    __syncthreads();
    if (l == 0) { red[wv] = t0; red[4 + wv] = t1; }
    __syncthreads();
    if (t == 0) {
        osp[bs * 2 + 0] = wp0;
        osp[bs * 2 + 1] = wp1;
        oss[bs * 2 + 0] = fminf(fmaxf(sqrtf(red[0] + red[1] + red[2] + red[3]), 0.001f), 5.0f);
        oss[bs * 2 + 1] = fminf(fmaxf(sqrtf(red[4] + red[5] + red[6] + red[7]), 0.001f), 5.0f);
    }
    attn_out[((size_t)b * N + t) * S + s] = a_n * inv_sa;
}

extern "C" void kernel_launch(void* const* d_in, const int* in_sizes, int n_in,
                              void* d_out, int out_size, void* d_ws, size_t ws_size,
                              hipStream_t stream) {
    const float* inputs  = (const float*)d_in[0];
    const float* s_p0    = (const float*)d_in[1];
    const float* s_s0    = (const float*)d_in[2];
    const float* slots_mu= (const float*)d_in[3];
    const float* es_w1   = (const float*)d_in[4];
    const float* es_b1   = (const float*)d_in[5];
    const float* es_w2   = (const float*)d_in[6];
    const float* es_b2   = (const float*)d_in[7];
    const float* er_w    = (const float*)d_in[8];
    const float* er_b    = (const float*)d_in[9];
    const float* pk_w    = (const float*)d_in[10];
    const float* pk_b    = (const float*)d_in[11];
    const float* pv_w    = (const float*)d_in[12];
    const float* pv_b    = (const float*)d_in[13];
    const float* pq_w    = (const float*)d_in[14];
    const float* pq_b    = (const float*)d_in[15];
    const float* mi_w1   = (const float*)d_in[16];
    const float* mi_b1   = (const float*)d_in[17];
    const float* mi_w2   = (const float*)d_in[18];
    const float* mi_b2   = (const float*)d_in[19];
    const float* ns_g    = (const float*)d_in[20];
    const float* ns_b    = (const float*)d_in[21];
    const float* nm_g    = (const float*)d_in[22];
    const float* nm_b    = (const float*)d_in[23];
    const float* gru_k   = (const float*)d_in[24];
    const float* gru_rk  = (const float*)d_in[25];
    const float* gru_b   = (const float*)d_in[26];
    const float* mlp_w1  = (const float*)d_in[27];
    const float* mlp_b1  = (const float*)d_in[28];
    const float* mlp_w2  = (const float*)d_in[29];
    const float* mlp_b2  = (const float*)d_in[30];

    float* ws    = (float*)d_ws;
    float* pos   = ws;                       // 131072
    float* GkT   = pos   + 131072;           // 1048576
    float* Gv    = GkT   + 1048576;          // 1048576
    float* vb    = Gv    + 1048576;          // 5767168
    float* lgts0 = vb    + 5767168;          // 90112
    float* lgts1 = lgts0 + 90112;            // 90112
    float* slots = lgts1 + 90112;            // 22528
    float* sp    = slots + 22528;            // 704
    float* ssg   = sp    + 704;              // 704
    float* w2qb  = ssg   + 704;              // 45056
    float* b2qb  = w2qb  + 45056;            // 352
    float* ewp   = b2qb  + 352;              // 512
    u16*   wkT   = (u16*)(ewp + 512);        // 65536 u16 (wvT follows)
    u16*   wvT   = wkT + 65536;              // 65536 u16
    u16*   w2t   = wvT + 65536;              // 8192 u16

    float* out      = (float*)d_out;
    float* out_sp   = out + B * S * D;            // 704
    float* out_ss   = out_sp + B * S * 2;         // 704
    float* attn_out = out_ss + B * S * 2;         // 90112

    pre1_kernel<<<890, 256, 0, stream>>>(es_w1, es_b1, es_w2, es_b2,
                                         mi_w1, mi_b1, mi_w2,
                                         pk_w, pk_b, pv_w, pv_b, er_w, er_b,
                                         slots_mu, s_p0, s_s0,
                                         pos, wkT, wvT, w2t, ewp, slots, sp, ssg);
    pre2_kernel<<<864, 256, 0, stream>>>(inputs, pos, wkT, slots,
                                         ns_g, ns_b, pq_w, pq_b, mi_w2, mi_b2,
                                         GkT, Gv, w2qb, b2qb);
    kv_kernel<<<704, 256, 0, stream>>>(GkT, Gv, ewp, sp, ssg,
                                       w2qb, b2qb, w2t, mi_b2, lgts0, vb);
    upkv_kernel<<<352, 512, 0, stream>>>(0, lgts0, lgts1, GkT, Gv, ewp, w2t, mi_b2,
                                         gru_k, gru_rk, gru_b, nm_g, nm_b,
                                         mlp_w1, mlp_b1, mlp_w2, mlp_b2,
                                         ns_g, ns_b, pq_w, pq_b, mi_w2,
                                         vb, slots, out);
    upkv_kernel<<<352, 512, 0, stream>>>(1, lgts1, lgts0, GkT, Gv, ewp, w2t, mi_b2,
                                         gru_k, gru_rk, gru_b, nm_g, nm_b,
                                         mlp_w1, mlp_b1, mlp_w2, mlp_b2,
                                         ns_g, ns_b, pq_w, pq_b, mi_w2,
                                         vb, slots, out);
    upkv_kernel<<<352, 512, 0, stream>>>(2, lgts0, lgts1, GkT, Gv, ewp, w2t, mi_b2,
                                         gru_k, gru_rk, gru_b, nm_g, nm_b,
                                         mlp_w1, mlp_b1, mlp_w2, mlp_b2,
                                         ns_g, ns_b, pq_w, pq_b, mi_w2,
                                         vb, slots, out);
    fin_kernel<<<352, 256, 0, stream>>>(lgts1, attn_out, out_sp, out_ss);
}

// Round 10
// 120.322 us; speedup vs baseline: 7.1756x; 1.5626x over previous
//
#include <hip/hip_runtime.h>
#include <cmath>

#define B 32
#define S 11
#define R 16
#define D 64
#define C 512
#define N 256   // R*R
#define LN_EPS 1e-3f

typedef unsigned short u16;
typedef unsigned int   u32;

using bf16x8 = __attribute__((ext_vector_type(8))) short;
using f32x4  = __attribute__((ext_vector_type(4))) float;

__device__ __forceinline__ float grid_coord(int i) {
    return -1.0f + (2.0f / 15.0f) * (float)i;
}

__device__ __forceinline__ u16 f2bf(float x) {
    union { float f; u32 u; } c; c.f = x;
    u32 r = c.u + 0x7fffu + ((c.u >> 16) & 1u);   // RNE
    return (u16)(r >> 16);
}

__device__ __forceinline__ float bf2f(u16 h) {
    union { u32 u; float f; } c; c.u = ((u32)h) << 16; return c.f;
}

// ============ PRE1: pos (0..255) | wprep wk/wv+ewp (256..769) | init (770..857)
__global__ __launch_bounds__(256) void pre1_kernel(
    const float* __restrict__ es_w1, const float* __restrict__ es_b1,
    const float* __restrict__ es_w2, const float* __restrict__ es_b2,
    const float* __restrict__ mi_w1, const float* __restrict__ mi_b1,
    const float* __restrict__ pk_w, const float* __restrict__ pk_b,
    const float* __restrict__ pv_w, const float* __restrict__ pv_b,
    const float* __restrict__ er_w, const float* __restrict__ er_b,
    const float* __restrict__ slots_mu, const float* __restrict__ s_p0,
    const float* __restrict__ s_s0,
    float* __restrict__ pos,
    u16* __restrict__ wkT, u16* __restrict__ wvT,
    float* __restrict__ ewp,
    float* __restrict__ slots0, float* __restrict__ sp0, float* __restrict__ ss0) {
    int bid = blockIdx.x;
    int t = threadIdx.x;
    if (bid < 256) {
        int n = bid;
        float g0 = grid_coord(n >> 4), g1 = grid_coord(n & 15);
        __shared__ float h[128];
        if (t < 128) {
            float hj = es_b1[t] + g0 * es_w1[t] + g1 * es_w1[128 + t];
            h[t] = fmaxf(hj, 0.0f);
        }
        __syncthreads();
        #pragma unroll
        for (int c0 = 0; c0 < C; c0 += 256) {
            int c = c0 + t;
            float acc = es_b2[c];
            #pragma unroll 16
            for (int jj = 0; jj < 128; ++jj) acc += h[jj] * es_w2[jj * C + c];
            pos[n * C + c] = acc;
        }
    } else if (bid < 770) {
        int idx = (bid - 256) * 256 + t;       // 0..131583
        if (idx < 131072) {
            int mat = idx >> 16;
            int i = idx & 65535;
            int c = i >> 7, j = i & 127;
            const float* pw = mat ? pv_w : pk_w;
            float acc = 0.f;
            #pragma unroll 8
            for (int k = 0; k < 64; ++k) acc += pw[c * 64 + k] * mi_w1[k * 128 + j];
            u16* dst = mat ? wvT : wkT;
            dst[j * 512 + c] = f2bf(acc);
        } else if (idx < 131584) {
            int i = idx - 131072;              // 0..511
            int tt = i >> 7, j = i & 127;
            float acc = 0.f;
            if (tt == 0) {
                for (int k = 0; k < 64; ++k) acc += er_w[k] * mi_w1[k * 128 + j];
            } else if (tt == 1) {
                for (int k = 0; k < 64; ++k) acc += er_w[64 + k] * mi_w1[k * 128 + j];
            } else if (tt == 2) {
                for (int k = 0; k < 64; ++k) acc += (pk_b[k] + er_b[k]) * mi_w1[k * 128 + j];
                acc += mi_b1[j];
            } else {
                for (int k = 0; k < 64; ++k) acc += (pv_b[k] + er_b[k]) * mi_w1[k * 128 + j];
                acc += mi_b1[j];
            }
            ewp[i] = acc;
        }
    } else {
        int idx = (bid - 770) * 256 + t;
        slots0[idx] = slots_mu[idx % (S * D)];
        if (idx < B * S * 2) { sp0[idx] = s_p0[idx]; ss0[idx] = s_s0[idx]; }
    }
}

// ============ PRE2: xw1 (0..511) | initial qw2q (512..863) ==================
// GkT[b][j][n] fp32 (bbk folded), Gv16[b][n][j] bf16 (bbv folded)
__global__ __launch_bounds__(256) void pre2_kernel(
    const float* __restrict__ inputs, const float* __restrict__ pos,
    const u16* __restrict__ wkT,      // wvT at +65536
    const float* __restrict__ ewp,
    const float* __restrict__ slots0,
    const float* __restrict__ ns_g, const float* __restrict__ ns_b,
    const float* __restrict__ pq_w, const float* __restrict__ pq_b,
    const float* __restrict__ mi_w2, const float* __restrict__ mi_b2,
    float* __restrict__ GkT, u16* __restrict__ Gv16,
    float* __restrict__ w2q, float* __restrict__ b2q) {
    int bid = blockIdx.x;
    int t = threadIdx.x;
    if (bid < 512) {
        int row0 = bid * 16;
        __shared__ u16 Xs[16 * 512];
        __shared__ float bbk2[128], bbv2[128];
        if (t < 128) { bbk2[t] = ewp[256 + t]; bbv2[t] = ewp[384 + t]; }
        const float4* in4 = (const float4*)(inputs + (size_t)row0 * C);
        #pragma unroll
        for (int it = 0; it < 8; ++it) {
            int f = it * 256 + t;
            int lr = f >> 7;
            int c = (f & 127) * 4;
            float4 a = in4[f];
            float4 p = *(const float4*)(pos + (size_t)((row0 + lr) & (N - 1)) * C + c);
            u32 lo = (u32)f2bf(a.x + p.x) | ((u32)f2bf(a.y + p.y) << 16);
            u32 hi = (u32)f2bf(a.z + p.z) | ((u32)f2bf(a.w + p.w) << 16);
            int cs = c ^ ((lr & 7) << 3);
            *(uint2*)&Xs[lr * 512 + cs] = make_uint2(lo, hi);
        }
        __syncthreads();

        int w = t >> 6, l = t & 63;
        int l16 = l & 15, lq = l >> 4;
        int wc = w * 32;
        int b = row0 >> 8, nb = row0 & (N - 1);

        f32x4 acc[2][2];
        #pragma unroll
        for (int m = 0; m < 2; ++m)
            #pragma unroll
            for (int nt = 0; nt < 2; ++nt) acc[m][nt] = (f32x4){0.f, 0.f, 0.f, 0.f};

        for (int kt = 0; kt < 16; ++kt) {
            int k0 = kt * 32 + lq * 8;
            int ks = k0 ^ ((l16 & 7) << 3);
            bf16x8 xf = *(const bf16x8*)&Xs[l16 * 512 + ks];
            #pragma unroll
            for (int m = 0; m < 2; ++m) {
                const u16* Wm = wkT + (size_t)m * 65536;
                #pragma unroll
                for (int nt = 0; nt < 2; ++nt) {
                    bf16x8 wf = *(const bf16x8*)(Wm + (size_t)(wc + nt * 16 + l16) * 512 + k0);
                    acc[m][nt] = __builtin_amdgcn_mfma_f32_16x16x32_bf16(xf, wf, acc[m][nt], 0, 0, 0);
                }
            }
        }
        #pragma unroll
        for (int nt = 0; nt < 2; ++nt) {
            #pragma unroll
            for (int r = 0; r < 4; ++r) {
                int j = wc + nt * 16 + l16;
                int n2 = nb + lq * 4 + r;
                GkT[((size_t)b * 128 + j) * 256 + n2] = acc[0][nt][r] + bbk2[j];
                Gv16[((size_t)b * 256 + n2) * 128 + j] = f2bf(acc[1][nt][r] + bbv2[j]);
            }
        }
    } else {
        int bs = bid - 512;
        __shared__ float xlds[64], qs[64];
        if (t < 64) {
            float x = slots0[bs * D + t];
            float sum = x;
            #pragma unroll
            for (int off = 32; off > 0; off >>= 1) sum += __shfl_xor(sum, off);
            float m = sum * (1.0f / 64.0f);
            float dx = x - m;
            float vs = dx * dx;
            #pragma unroll
            for (int off = 32; off > 0; off >>= 1) vs += __shfl_xor(vs, off);
            float var = vs * (1.0f / 64.0f);
            xlds[t] = dx * rsqrtf(var + LN_EPS) * ns_g[t] + ns_b[t];
        }
        __syncthreads();
        if (t < 64) {
            float acc = pq_b[t];
            #pragma unroll 8
            for (int i = 0; i < 64; ++i) acc += xlds[i] * pq_w[i * D + t];
            qs[t] = acc * 0.125f;
        }
        __syncthreads();
        if (t < 128) {
            float sacc = 0.f;
            #pragma unroll 8
            for (int dd = 0; dd < 64; ++dd) sacc += mi_w2[t * 64 + dd] * qs[dd];
            w2q[bs * 128 + t] = sacc;
        }
        if (t < 64) {
            float v = mi_b2[t] * qs[t];
            #pragma unroll
            for (int off = 32; off > 0; off >>= 1) v += __shfl_xor(v, off);
            if (t == 0) b2q[bs] = v;
        }
    }
}

// ============ KV0: iteration-0 logits only ==================================
__global__ __launch_bounds__(256) void kv0_kernel(
    const float* __restrict__ GkT, const float* __restrict__ ewp,
    const float* __restrict__ sp0, const float* __restrict__ ss0,
    const float* __restrict__ w2q, const float* __restrict__ b2q,
    float* __restrict__ logits) {
    int orig = blockIdx.x;                       // 704 = 8*88
    int u = (orig & 7) * 88 + (orig >> 3);
    int half = u & 1, bs = u >> 1;
    int b = bs / S, s = bs - b * S;
    int t = threadIdx.x;
    __shared__ float e0s[128], e1s[128], wqs[128], lgp[128], rl0[128], rl1[128];
    if (t < 128) {
        e0s[t] = ewp[t]; e1s[t] = ewp[128 + t];
        wqs[t] = w2q[bs * 128 + t];
        float p0 = sp0[bs * 2 + 0], p1 = sp0[bs * 2 + 1];
        float q0 = ss0[bs * 2 + 0], q1 = ss0[bs * 2 + 1];
        int n = half * 128 + t;
        rl0[t] = (grid_coord(n >> 4) - p0) / q0;
        rl1[t] = (grid_coord(n & 15) - p1) / q1;
    }
    __syncthreads();
    int n_loc = t & 127, jh = t >> 7;
    float r0 = rl0[n_loc], r1 = rl1[n_loc];
    const float* Gb = GkT + ((size_t)b * 128 + jh * 64) * 256 + half * 128 + n_loc;
    float acc = 0.f;
    #pragma unroll 8
    for (int j = 0; j < 64; ++j) {
        int jj = jh * 64 + j;
        float h = Gb[(size_t)j * 256] + r0 * e0s[jj] + r1 * e1s[jj];
        acc += fmaxf(h, 0.f) * wqs[jj];
    }
    if (jh) lgp[n_loc] = acc;
    __syncthreads();
    if (!jh)
        logits[((size_t)b * S + s) * N + half * 128 + n_loc] = acc + lgp[n_loc] + b2q[bs];
}

// ============ UPKV: update(ind) [duplicated per half] + logits(ind+1) =======
__global__ __launch_bounds__(256) void upkv_kernel(
    int ind,
    const float* __restrict__ lgts_r, float* __restrict__ lgts_w,
    const float* __restrict__ sp_r, const float* __restrict__ ss_r,
    float* __restrict__ sp_w, float* __restrict__ ss_w,
    const float* __restrict__ slots_r, float* __restrict__ slots_w,
    const float* __restrict__ GkT, const u16* __restrict__ Gv16,
    const float* __restrict__ ewp,
    const float* __restrict__ gru_k, const float* __restrict__ gru_rk,
    const float* __restrict__ gru_b,
    const float* __restrict__ nm_g, const float* __restrict__ nm_b,
    const float* __restrict__ mlp_w1, const float* __restrict__ mlp_b1,
    const float* __restrict__ mlp_w2, const float* __restrict__ mlp_b2,
    const float* __restrict__ ns_g, const float* __restrict__ ns_b,
    const float* __restrict__ pq_w, const float* __restrict__ pq_b,
    const float* __restrict__ mi_w2, const float* __restrict__ mi_b2,
    float* __restrict__ out_slots) {
    int orig = blockIdx.x;                 // 704 = 8*88
    int u = (orig & 7) * 88 + (orig >> 3);
    int half = u & 1, bs = u >> 1;
    int b = bs / S, s = bs - b * S;
    int t = threadIdx.x;
    int wv = t >> 6, l = t & 63, d = l;

    __shared__ float e0s[128], e1s[128], wqs[128], lgp[128];
    __shared__ float rlo0[256], rlo1[256], rn0[128], rn1[128];
    __shared__ float a_l[256], aH2[256], ul[64], hl[64], gx[192], gh[192];
    __shared__ float xl[64], snl[64], hb[128], xq[64], qs[64], red[12], sc[4];

    if (t < 128) { e0s[t] = ewp[t]; e1s[t] = ewp[128 + t]; }
    {   // rl of THIS iteration (for H recompute) from ping-ponged s_p/s_s
        float p0 = sp_r[bs * 2 + 0], p1 = sp_r[bs * 2 + 1];
        float q0 = ss_r[bs * 2 + 0], q1 = ss_r[bs * 2 + 1];
        rlo0[t] = (grid_coord(t >> 4) - p0) / q0;
        rlo1[t] = (grid_coord(t & 15) - p1) / q1;
    }

    // ---- softmax over slots at n = t ----
    float m = -1e30f, lg[S];
    #pragma unroll
    for (int ss2 = 0; ss2 < S; ++ss2) {
        lg[ss2] = lgts_r[((size_t)b * S + ss2) * N + t];
        m = fmaxf(m, lg[ss2]);
    }
    float sum = 0.f, e_own = 0.f;
    #pragma unroll
    for (int ss2 = 0; ss2 < S; ++ss2) {
        float e = expf(lg[ss2] - m);
        sum += e;
        if (ss2 == s) e_own = e;
    }
    float a_n = e_own / sum + 1e-8f;
    float g0 = grid_coord(t >> 4), g1 = grid_coord(t & 15);
    {
        float sa = a_n, s0 = a_n * g0, s1 = a_n * g1;
        #pragma unroll
        for (int off = 32; off > 0; off >>= 1) {
            sa += __shfl_xor(sa, off);
            s0 += __shfl_xor(s0, off);
            s1 += __shfl_xor(s1, off);
        }
        if (l == 0) { red[wv] = sa; red[4 + wv] = s0; red[8 + wv] = s1; }
    }
    __syncthreads();
    float SA = red[0] + red[1] + red[2] + red[3];
    float wp0 = (red[4] + red[5] + red[6] + red[7]) / SA;
    float wp1 = (red[8] + red[9] + red[10] + red[11]) / SA;
    float inv_sa = 1.0f / SA;
    __syncthreads();
    {
        float av = a_n * inv_sa + 1e-11f;
        float d0 = g0 - wp0, d1 = g1 - wp1;
        float t0 = d0 * d0 * av, t1 = d1 * d1 * av;
        #pragma unroll
        for (int off = 32; off > 0; off >>= 1) {
            t0 += __shfl_xor(t0, off);
            t1 += __shfl_xor(t1, off);
        }
        if (l == 0) { red[wv] = t0; red[4 + wv] = t1; }
        a_l[t] = a_n * inv_sa;
    }
    __syncthreads();
    float T0c = fminf(fmaxf(sqrtf(red[0] + red[1] + red[2] + red[3]), 0.001f), 5.0f);
    float T1c = fminf(fmaxf(sqrtf(red[4] + red[5] + red[6] + red[7]), 0.001f), 5.0f);

    // ---- aH[j] = sum_n a_l[n] * relu(Gv'[n][j] + rank2(rl_old)) ----
    {
        int j = t & 127, nh = t >> 7;
        const u16* Gr = Gv16 + ((size_t)b * 256 + nh * 128) * 128 + j;
        float e0j = e0s[j], e1j = e1s[j];
        float acc = 0.f;
        #pragma unroll 8
        for (int i = 0; i < 128; ++i) {
            int n = nh * 128 + i;
            float h = bf2f(Gr[(size_t)i * 128]) + rlo0[n] * e0j + rlo1[n] * e1j;
            acc += a_l[n] * fmaxf(h, 0.f);
        }
        aH2[t] = acc;
    }
    __syncthreads();
    // ---- updates = aH @ W2 + b2 ----
    if (t < 64) {
        float u2 = mi_b2[d];
        #pragma unroll 8
        for (int j = 0; j < 128; ++j)
            u2 += (aH2[j] + aH2[128 + j]) * mi_w2[j * 64 + d];
        ul[d] = u2;
        hl[d] = slots_r[bs * D + d];
    }
    __syncthreads();
    if (t < 192) {
        float ax = gru_b[t], ah = gru_b[192 + t];
        #pragma unroll 8
        for (int i = 0; i < 64; ++i) {
            ax += ul[i] * gru_k[i * 192 + t];
            ah += hl[i] * gru_rk[i * 192 + t];
        }
        gx[t] = ax; gh[t] = ah;
    }
    __syncthreads();
    if (t < 64) {
        float z = 1.f / (1.f + expf(-(gx[d] + gh[d])));
        float r = 1.f / (1.f + expf(-(gx[64 + d] + gh[64 + d])));
        float hc = tanhf(gx[128 + d] + r * gh[128 + d]);
        float sn = z * hl[d] + (1.f - z) * hc;
        snl[d] = sn;
        float sm = sn;
        #pragma unroll
        for (int off = 32; off > 0; off >>= 1) sm += __shfl_xor(sm, off);
        float mm = sm * (1.0f / 64.0f);
        float dx = sn - mm;
        float vs = dx * dx;
        #pragma unroll
        for (int off = 32; off > 0; off >>= 1) vs += __shfl_xor(vs, off);
        float var = vs * (1.0f / 64.0f);
        xl[d] = dx * rsqrtf(var + LN_EPS) * nm_g[d] + nm_b[d];
    }
    __syncthreads();
    if (t < 128) {
        float h1 = mlp_b1[t];
        #pragma unroll 8
        for (int i = 0; i < 64; ++i) h1 += xl[i] * mlp_w1[i * 128 + t];
        hb[t] = fmaxf(h1, 0.f);
    }
    __syncthreads();
    if (t < 64) {
        float o = mlp_b2[d];
        #pragma unroll 8
        for (int j = 0; j < 128; ++j) o += hb[j] * mlp_w2[j * D + d];
        float res = snl[d] + o;
        slots_w[bs * D + d] = res;
        if (ind == 2) out_slots[bs * D + d] = res;
        float sm = res;
        #pragma unroll
        for (int off = 32; off > 0; off >>= 1) sm += __shfl_xor(sm, off);
        float mm = sm * (1.0f / 64.0f);
        float dx = res - mm;
        float vs = dx * dx;
        #pragma unroll
        for (int off = 32; off > 0; off >>= 1) vs += __shfl_xor(vs, off);
        float var = vs * (1.0f / 64.0f);
        xq[d] = dx * rsqrtf(var + LN_EPS) * ns_g[d] + ns_b[d];
    }
    __syncthreads();
    if (t < 64) {
        float acc = pq_b[d];
        #pragma unroll 8
        for (int i = 0; i < 64; ++i) acc += xq[i] * pq_w[i * D + d];
        qs[d] = acc * 0.125f;
    }
    __syncthreads();
    {
        float wql = 0.f;
        if (t < 128) {
            #pragma unroll 8
            for (int dd = 0; dd < 64; ++dd) wql += mi_w2[t * 64 + dd] * qs[dd];
        }
        float b2v = 0.f;
        if (t < 64) {
            b2v = mi_b2[d] * qs[d];
            #pragma unroll
            for (int off = 32; off > 0; off >>= 1) b2v += __shfl_xor(b2v, off);
        }
        if (t < 128) wqs[t] = wql;
        if (t == 0) {
            sc[0] = b2v;
            sp_w[bs * 2 + 0] = wp0; sp_w[bs * 2 + 1] = wp1;
            ss_w[bs * 2 + 0] = T0c; ss_w[bs * 2 + 1] = T1c;
        }
        if (t < 128) {
            int n = half * 128 + t;
            rn0[t] = (grid_coord(n >> 4) - wp0) / T0c;
            rn1[t] = (grid_coord(n & 15) - wp1) / T1c;
        }
    }
    __syncthreads();

    // ---- Phase K: logits(ind+1) for own half ----
    {
        int n_loc = t & 127, jh = t >> 7;
        float r0 = rn0[n_loc], r1 = rn1[n_loc];
        const float* Gb = GkT + ((size_t)b * 128 + jh * 64) * 256 + half * 128 + n_loc;
        float acc = 0.f;
        #pragma unroll 8
        for (int j = 0; j < 64; ++j) {
            int jj = jh * 64 + j;
            float h = Gb[(size_t)j * 256] + r0 * e0s[jj] + r1 * e1s[jj];
            acc += fmaxf(h, 0.f) * wqs[jj];
        }
        if (jh) lgp[n_loc] = acc;
        __syncthreads();
        if (!jh)
            lgts_w[((size_t)b * S + s) * N + half * 128 + n_loc] = acc + lgp[n_loc] + sc[0];
    }
}

// ============ FIN: final softmax/calcSP -> attn_out, osp, oss ===============
__global__ __launch_bounds__(256) void fin_kernel(
    const float* __restrict__ lgts_r,
    float* __restrict__ attn_out, float* __restrict__ osp, float* __restrict__ oss) {
    int orig = blockIdx.x;
    int bs = (orig & 7) * 44 + (orig >> 3);
    int b = bs / S, s = bs - b * S;
    int t = threadIdx.x;
    int wv = t >> 6, l = t & 63;
    __shared__ float red[12];
    float m = -1e30f, lg[S];
    #pragma unroll
    for (int ss2 = 0; ss2 < S; ++ss2) {
        lg[ss2] = lgts_r[((size_t)b * S + ss2) * N + t];
        m = fmaxf(m, lg[ss2]);
    }
    float sum = 0.f, e_own = 0.f;
    #pragma unroll
    for (int ss2 = 0; ss2 < S; ++ss2) {
        float e = expf(lg[ss2] - m);
        sum += e;
        if (ss2 == s) e_own = e;
    }
    float a_n = e_own / sum + 1e-8f;
    float g0 = grid_coord(t >> 4), g1 = grid_coord(t & 15);
    float sa = a_n, s0 = a_n * g0, s1 = a_n * g1;
    #pragma unroll
    for (int off = 32; off > 0; off >>= 1) {
        sa += __shfl_xor(sa, off);
        s0 += __shfl_xor(s0, off);
        s1 += __shfl_xor(s1, off);
    }
    if (l == 0) { red[wv] = sa; red[4 + wv] = s0; red[8 + wv] = s1; }
    __syncthreads();
    float SA = red[0] + red[1] + red[2] + red[3];
    float wp0 = (red[4] + red[5] + red[6] + red[7]) / SA;
    float wp1 = (red[8] + red[9] + red[10] + red[11]) / SA;
    float inv_sa = 1.0f / SA;
    float av = a_n * inv_sa + 1e-11f;
    float d0 = g0 - wp0, d1 = g1 - wp1;
    float t0 = d0 * d0 * av, t1 = d1 * d1 * av;
    #pragma unroll
    for (int off = 32; off > 0; off >>= 1) {
        t0 += __shfl_xor(t0, off);
        t1 += __shfl_xor(t1, off);
    }
    __syncthreads();
    if (l == 0) { red[wv] = t0; red[4 + wv] = t1; }
    __syncthreads();
    if (t == 0) {
        osp[bs * 2 + 0] = wp0;
        osp[bs * 2 + 1] = wp1;
        oss[bs * 2 + 0] = fminf(fmaxf(sqrtf(red[0] + red[1] + red[2] + red[3]), 0.001f), 5.0f);
        oss[bs * 2 + 1] = fminf(fmaxf(sqrtf(red[4] + red[5] + red[6] + red[7]), 0.001f), 5.0f);
    }
    attn_out[((size_t)b * N + t) * S + s] = a_n * inv_sa;
}

extern "C" void kernel_launch(void* const* d_in, const int* in_sizes, int n_in,
                              void* d_out, int out_size, void* d_ws, size_t ws_size,
                              hipStream_t stream) {
    const float* inputs  = (const float*)d_in[0];
    const float* s_p0    = (const float*)d_in[1];
    const float* s_s0    = (const float*)d_in[2];
    const float* slots_mu= (const float*)d_in[3];
    const float* es_w1   = (const float*)d_in[4];
    const float* es_b1   = (const float*)d_in[5];
    const float* es_w2   = (const float*)d_in[6];
    const float* es_b2   = (const float*)d_in[7];
    const float* er_w    = (const float*)d_in[8];
    const float* er_b    = (const float*)d_in[9];
    const float* pk_w    = (const float*)d_in[10];
    const float* pk_b    = (const float*)d_in[11];
    const float* pv_w    = (const float*)d_in[12];
    const float* pv_b    = (const float*)d_in[13];
    const float* pq_w    = (const float*)d_in[14];
    const float* pq_b    = (const float*)d_in[15];
    const float* mi_w1   = (const float*)d_in[16];
    const float* mi_b1   = (const float*)d_in[17];
    const float* mi_w2   = (const float*)d_in[18];
    const float* mi_b2   = (const float*)d_in[19];
    const float* ns_g    = (const float*)d_in[20];
    const float* ns_b    = (const float*)d_in[21];
    const float* nm_g    = (const float*)d_in[22];
    const float* nm_b    = (const float*)d_in[23];
    const float* gru_k   = (const float*)d_in[24];
    const float* gru_rk  = (const float*)d_in[25];
    const float* gru_b   = (const float*)d_in[26];
    const float* mlp_w1  = (const float*)d_in[27];
    const float* mlp_b1  = (const float*)d_in[28];
    const float* mlp_w2  = (const float*)d_in[29];
    const float* mlp_b2  = (const float*)d_in[30];

    float* ws     = (float*)d_ws;
    float* pos    = ws;                        // 131072
    float* GkT    = pos    + 131072;           // 1048576 (fp32, bias folded)
    u16*   Gv16   = (u16*)(GkT + 1048576);     // 2097152 u16 = 1048576 floats
    float* lgts0  = GkT + 2097152;             // 90112
    float* lgts1  = lgts0  + 90112;            // 90112
    float* slots0 = lgts1  + 90112;            // 22528
    float* slots1 = slots0 + 22528;            // 22528
    float* sp0    = slots1 + 22528;            // 704
    float* ss0    = sp0    + 704;              // 704
    float* sp1    = ss0    + 704;              // 704
    float* ss1    = sp1    + 704;              // 704
    float* w2qb   = ss1    + 704;              // 45056
    float* b2qb   = w2qb   + 45056;            // 352
    float* ewp    = b2qb   + 352;              // 512
    u16*   wkT    = (u16*)(ewp + 512);         // 65536 u16 (wvT follows)
    u16*   wvT    = wkT + 65536;               // 65536 u16

    float* out      = (float*)d_out;
    float* out_sp   = out + B * S * D;
    float* out_ss   = out_sp + B * S * 2;
    float* attn_out = out_ss + B * S * 2;

    pre1_kernel<<<858, 256, 0, stream>>>(es_w1, es_b1, es_w2, es_b2,
                                         mi_w1, mi_b1,
                                         pk_w, pk_b, pv_w, pv_b, er_w, er_b,
                                         slots_mu, s_p0, s_s0,
                                         pos, wkT, wvT, ewp, slots0, sp0, ss0);
    pre2_kernel<<<864, 256, 0, stream>>>(inputs, pos, wkT, ewp, slots0,
                                         ns_g, ns_b, pq_w, pq_b, mi_w2, mi_b2,
                                         GkT, Gv16, w2qb, b2qb);
    kv0_kernel<<<704, 256, 0, stream>>>(GkT, ewp, sp0, ss0, w2qb, b2qb, lgts0);
    upkv_kernel<<<704, 256, 0, stream>>>(0, lgts0, lgts1, sp0, ss0, sp1, ss1,
                                         slots0, slots1, GkT, Gv16, ewp,
                                         gru_k, gru_rk, gru_b, nm_g, nm_b,
                                         mlp_w1, mlp_b1, mlp_w2, mlp_b2,
                                         ns_g, ns_b, pq_w, pq_b, mi_w2, mi_b2, out);
    upkv_kernel<<<704, 256, 0, stream>>>(1, lgts1, lgts0, sp1, ss1, sp0, ss0,
                                         slots1, slots0, GkT, Gv16, ewp,
                                         gru_k, gru_rk, gru_b, nm_g, nm_b,
                                         mlp_w1, mlp_b1, mlp_w2, mlp_b2,
                                         ns_g, ns_b, pq_w, pq_b, mi_w2, mi_b2, out);
    upkv_kernel<<<704, 256, 0, stream>>>(2, lgts0, lgts1, sp0, ss0, sp1, ss1,
                                         slots0, slots1, GkT, Gv16, ewp,
                                         gru_k, gru_rk, gru_b, nm_g, nm_b,
                                         mlp_w1, mlp_b1, mlp_w2, mlp_b2,
                                         ns_g, ns_b, pq_w, pq_b, mi_w2, mi_b2, out);
    fin_kernel<<<352, 256, 0, stream>>>(lgts1, attn_out, out_sp, out_ss);
}